// Round 9
// baseline (395.948 us; speedup 1.0000x reference)
//
#include <hip/hip_runtime.h>
#include <hip/hip_bf16.h>
#include <math.h>

// Problem constants
#define BB 4
#define CC 128
#define NN 4096      // H*W
#define DD 256
#define INNER 512
#define FFD 1024
#define PP 4
#define LL 2
#define NT 8
#define SS 1024      // NN/PP
#define SCALE 0.0625f // 1/sqrt(256)

typedef __attribute__((ext_vector_type(8))) short bf16x8;
typedef __attribute__((ext_vector_type(8))) short short8;
typedef __attribute__((ext_vector_type(4))) float f32x4;

#define GLD_LDS16(g, l) __builtin_amdgcn_global_load_lds( \
    (const __attribute__((address_space(1))) void*)(g), \
    (__attribute__((address_space(3))) void*)(l), 16, 0, 0)

template<int NW>
__device__ inline float block_sum(float v, float* sbuf){
  #pragma unroll
  for (int mk=32; mk; mk>>=1) v += __shfl_xor(v, mk);
  int w = threadIdx.x>>6;
  if ((threadIdx.x&63)==0) sbuf[w]=v;
  __syncthreads();
  float r = 0.f;
  #pragma unroll
  for (int k=0;k<NW;k++) r += sbuf[k];
  __syncthreads();
  return r;
}

__device__ inline unsigned short bf16bits(float v){
  __hip_bfloat16 t = __float2bfloat16(v);
  unsigned short u;
  __builtin_memcpy(&u, &t, 2);
  return u;
}
__device__ inline float bf2f(unsigned short u){
  unsigned int x = ((unsigned int)u)<<16;
  float f;
  __builtin_memcpy(&f, &x, 4);
  return f;
}

// fast GELU: erf via Abramowitz-Stegun 7.1.26 (|eps| <= 1.5e-7)
__device__ inline float gelu_f(float x){
  float z  = x * 0.70710678118654752440f;
  float az = fabsf(z);
  float t  = 1.0f / (1.0f + 0.3275911f*az);
  float y  = t*(0.254829592f + t*(-0.284496736f + t*(1.421413741f +
             t*(-1.453152027f + t*1.061405429f))));
  float erfv = 1.0f - y*__expf(-az*az);
  erfv = (z < 0.0f) ? -erfv : erfv;
  return 0.5f*x*(1.0f+erfv);
}

// K2: merged scorer: ksc (LDS only), then kk2/kb/vsc outputs
__global__ __launch_bounds__(256) void scorer_kk2_kernel(
    const float* __restrict__ m, const float* __restrict__ sk_w,
    const float* __restrict__ sk_b, const float* __restrict__ sv_w,
    const float* __restrict__ sv_b, const float* __restrict__ sq_w,
    const float* __restrict__ sq_b,
    float* __restrict__ kk2, float* __restrict__ kb, float* __restrict__ vsc)
{
  int bj = blockIdx.x;               // B*NT = 32
  int d = threadIdx.x;
  __shared__ float ms[256];
  __shared__ float ks[256];
  __shared__ float sbuf[4];
  ms[d] = m[bj*DD + d];
  __syncthreads();
  float acc=0.f;
  for(int c=0;c<DD;c++) acc = fmaf(ms[c], sk_w[c*DD + d], acc);
  ks[d] = acc + sk_b[d];
  float sv = block_sum<4>(ms[d]*sv_w[d], sbuf);
  if(d==0) vsc[bj] = sv + sv_b[0];
  __syncthreads();
  const float* wr = sq_w + (long)d*DD;
  float a2 = 0.f;
  for (int c=0; c<DD; c+=4){
    float4 wv = *(const float4*)(wr + c);
    a2 = fmaf(wv.x, ks[c+0], fmaf(wv.y, ks[c+1], fmaf(wv.z, ks[c+2], fmaf(wv.w, ks[c+3], a2))));
  }
  kk2[bj*DD + d] = a2;
  float kbv = block_sum<4>(sq_b[d]*ks[d], sbuf);
  if (d==0) kb[bj] = kbv;
}

// K1: tokens = LN(conv1x1(x)) AND scores via factored scorer. 16 tokens/block.
__global__ __launch_bounds__(256) void proj_ln_score_kernel(
    const float* __restrict__ x, const float* __restrict__ proj_w,
    const float* __restrict__ proj_b, const float* __restrict__ lnp_g,
    const float* __restrict__ lnp_b, const float* __restrict__ kk2,
    const float* __restrict__ kb, const float* __restrict__ vsc,
    float* __restrict__ tokens, float* __restrict__ scores)
{
  int b  = blockIdx.x >> 8;
  int n0 = (blockIdx.x & 255) * 16;
  int tid = threadIdx.x;
  __shared__ float xs[16][132];
  __shared__ float ys[16][260];
  __shared__ float kj[8][260];
  __shared__ float kbs[8], vs[8];
  __shared__ float mu_s[16], rs_s[16];
  __shared__ float lg[16][8];
  #pragma unroll
  for (int i=0;i<8;i++){
    int l = tid + i*256;
    int t = l & 15, c = l >> 4;
    xs[t][c] = x[(long)(b*CC + c)*NN + n0 + t];
  }
  #pragma unroll
  for (int i=0;i<8;i++){
    int idx = i*256 + tid;
    int r = idx >> 8, c = idx & 255;
    kj[r][c] = kk2[(b*NT + r)*DD + c];
  }
  if (tid < 8){ kbs[tid] = kb[b*NT+tid]; vs[tid] = vsc[b*NT+tid]; }
  __syncthreads();
  float acc[16];
  #pragma unroll
  for (int t=0;t<16;t++) acc[t]=0.f;
  for (int c0=0;c0<CC;c0+=4){
    float w0 = proj_w[(c0+0)*DD + tid];
    float w1_ = proj_w[(c0+1)*DD + tid];
    float w2_ = proj_w[(c0+2)*DD + tid];
    float w3_ = proj_w[(c0+3)*DD + tid];
    #pragma unroll
    for (int t=0;t<16;t++){
      float4 xv = *(const float4*)&xs[t][c0];
      acc[t] = fmaf(xv.x,w0,fmaf(xv.y,w1_,fmaf(xv.z,w2_,fmaf(xv.w,w3_,acc[t]))));
    }
  }
  float pb = proj_b[tid];
  #pragma unroll
  for (int t=0;t<16;t++) ys[t][tid] = acc[t] + pb;
  __syncthreads();
  int w = tid>>6, lane = tid&63;
  for (int k=0;k<4;k++){
    int t = w*4+k;
    float s = ys[t][lane] + ys[t][lane+64] + ys[t][lane+128] + ys[t][lane+192];
    #pragma unroll
    for (int mk=32; mk; mk>>=1) s += __shfl_xor(s, mk);
    float mu = s*(1.0f/256.0f);
    float d0=ys[t][lane]-mu, d1=ys[t][lane+64]-mu, d2=ys[t][lane+128]-mu, d3=ys[t][lane+192]-mu;
    float q = d0*d0+d1*d1+d2*d2+d3*d3;
    #pragma unroll
    for (int mk=32; mk; mk>>=1) q += __shfl_xor(q, mk);
    if (lane==0){ mu_s[t]=mu; rs_s[t]=rsqrtf(q*(1.0f/256.0f)+1e-5f); }
  }
  __syncthreads();
  float g = lnp_g[tid], be = lnp_b[tid];
  #pragma unroll
  for (int t=0;t<16;t++){
    float nv = (ys[t][tid]-mu_s[t])*rs_s[t]*g + be;
    tokens[((long)(b*NN + n0 + t))*DD + tid] = nv;
    ys[t][tid] = nv;
  }
  __syncthreads();
  if (tid < 128){
    int t = tid>>3, j = tid&7;
    float a2 = 0.f;
    for (int c0=0;c0<DD;c0+=4){
      float4 tv = *(const float4*)&ys[t][c0];
      float4 kv = *(const float4*)&kj[j][c0];
      a2 = fmaf(tv.x,kv.x,fmaf(tv.y,kv.y,fmaf(tv.z,kv.z,fmaf(tv.w,kv.w,a2))));
    }
    lg[t][j] = (a2 + kbs[j]) * SCALE;
  }
  __syncthreads();
  if (tid < 16){
    float mx=-1e30f;
    #pragma unroll
    for(int j=0;j<NT;j++) mx=fmaxf(mx,lg[tid][j]);
    float s=0.f, sc=0.f;
    #pragma unroll
    for(int j=0;j<NT;j++){ float e=__expf(lg[tid][j]-mx); s+=e; sc+=e*vs[j]; }
    scores[b*NN + n0 + tid] = sc/s;
  }
}

// K3a: partial ranks
__global__ __launch_bounds__(256) void rank_partial_kernel(
    const float* __restrict__ scores, int* __restrict__ rank)
{
  int b  = blockIdx.x >> 8;
  int it = (blockIdx.x >> 4) & 15;
  int jt = blockIdx.x & 15;
  int i = it*256 + threadIdx.x;
  float si = scores[b*NN + i];
  __shared__ float ss[256];
  ss[threadIdx.x] = scores[b*NN + jt*256 + threadIdx.x];
  __syncthreads();
  int jbase = jt*256;
  int cnt = 0;
  #pragma unroll 4
  for (int j=0;j<256;j++){
    float sj = ss[j];
    cnt += (sj > si) || (sj == si && (jbase+j) < i);
  }
  atomicAdd(&rank[b*NN+i], cnt);
}

// K3b
__global__ __launch_bounds__(256) void rank_finalize_kernel(
    const int* __restrict__ rank, int* __restrict__ cidx)
{
  int b = blockIdx.x >> 4;
  int i = (blockIdx.x & 15)*256 + threadIdx.x;
  int rk = rank[b*NN + i];
  int p = rk >> 10;
  cidx[(b*PP + p)*SS + (rk & (SS-1))] = i;
}

// K4
__global__ __launch_bounds__(1024) void pscore_pw_kernel(
    const float* __restrict__ scores, const int* __restrict__ cidx,
    float* __restrict__ pw)
{
  __shared__ float ps[16];
  int wv = threadIdx.x>>6;
  int lane = threadIdx.x&63;
  int b = wv>>2;
  float acc=0.f;
  for (int s=lane; s<SS; s+=64) acc += scores[b*NN + cidx[wv*SS + s]];
  #pragma unroll
  for (int mk=32; mk; mk>>=1) acc += __shfl_xor(acc, mk);
  if (lane==0) ps[wv] = acc*(1.0f/(float)SS);
  __syncthreads();
  if (threadIdx.x < BB){
    int bb = threadIdx.x;
    float mx=-1e30f;
    #pragma unroll
    for(int p=0;p<PP;p++) mx=fmaxf(mx,ps[bb*PP+p]);
    float s=0.f,e[PP];
    #pragma unroll
    for(int p=0;p<PP;p++){ e[p]=__expf(ps[bb*PP+p]-mx); s+=e[p]; }
    #pragma unroll
    for(int p=0;p<PP;p++) pw[bb*PP+p]=e[p]/s;
  }
}

// K6: gather + LN(an[p,0]) fused
__global__ __launch_bounds__(256) void gather_ln_kernel(
    const float* __restrict__ tokens, const int* __restrict__ cidx,
    float* __restrict__ Xc, __hip_bfloat16* __restrict__ Y,
    const float* __restrict__ gamma, const float* __restrict__ beta)
{
  long slot = (long)blockIdx.x*8 + (threadIdx.x>>5);
  int l32 = threadIdx.x & 31;
  int b = (int)(slot >> 12);
  int p = (int)((slot>>10)&3);
  int i = cidx[slot];
  const float* src = tokens + ((long)b*NN + i)*DD + l32*8;
  float4 v0 = *(const float4*)src;
  float4 v1 = *(const float4*)(src+4);
  *(float4*)(Xc + slot*DD + l32*8) = v0;
  *(float4*)(Xc + slot*DD + l32*8 + 4) = v1;
  float s = v0.x+v0.y+v0.z+v0.w+v1.x+v1.y+v1.z+v1.w;
  #pragma unroll
  for (int mk=16; mk; mk>>=1) s += __shfl_xor(s, mk);
  float mu = s*(1.0f/256.0f);
  float vv[8] = {v0.x,v0.y,v0.z,v0.w,v1.x,v1.y,v1.z,v1.w};
  float q = 0.f;
  #pragma unroll
  for (int k=0;k<8;k++){ float d = vv[k]-mu; q += d*d; }
  #pragma unroll
  for (int mk=16; mk; mk>>=1) q += __shfl_xor(q, mk);
  float rs = rsqrtf(q*(1.0f/256.0f)+1e-5f);
  short8 o;
  #pragma unroll
  for (int k=0;k<8;k++){
    int d = l32*8+k;
    o[k] = (short)bf16bits((vv[k]-mu)*rs*gamma[p*(LL*DD)+d]+beta[p*(LL*DD)+d]);
  }
  *(short8*)(Y + slot*DD + l32*8) = o;
}

// K7: decoder K/V precompute (plain layout)
__global__ __launch_bounds__(512) void kv_kernel(
    const float* __restrict__ m, const float* __restrict__ an_g,
    const float* __restrict__ an_b, const float* __restrict__ wk,
    const float* __restrict__ wv, float* __restrict__ kvk, float* __restrict__ kvv)
{
  int idx = blockIdx.x;              // (pl*B + b)*NT + j, grid 256
  int j = idx & 7, b = (idx>>3)&3, pl = idx>>5;
  int tid = threadIdx.x;
  __shared__ float mn[256];
  __shared__ float sbuf[8];
  float v = (tid<256) ? m[(b*NT+j)*DD + tid] : 0.0f;
  float s = block_sum<8>(v, sbuf);
  float mu = s*(1.0f/256.0f);
  float dv = (tid<256)? v-mu : 0.0f;
  float q = block_sum<8>(dv*dv, sbuf);
  float rs = rsqrtf(q*(1.0f/256.0f)+1e-5f);
  if (tid<256) mn[tid] = dv*rs*an_g[pl*DD+tid] + an_b[pl*DD+tid];
  __syncthreads();
  float ka=0.f, va=0.f;
  for (int c=0;c<DD;c++){
    float mc = mn[c];
    ka = fmaf(mc, wk[((long)pl*DD + c)*INNER + tid], ka);
    va = fmaf(mc, wv[((long)pl*DD + c)*INNER + tid], va);
  }
  long off = ((long)pl*BB + b)*(NT*INNER) + j*INNER + tid;
  kvk[off]=ka; kvv[off]=va;
}

// K8: rowwise LN -> bf16
__global__ __launch_bounds__(256) void ln_rows_kernel(
    const float* __restrict__ X, __hip_bfloat16* __restrict__ Y,
    const float* __restrict__ gamma, const float* __restrict__ beta)
{
  long row = (long)blockIdx.x*8 + (threadIdx.x>>5);
  int l32 = threadIdx.x & 31;
  int p = (int)((row>>10)&3);
  const float* xr = X + row*DD + l32*8;
  float4 v0 = *(const float4*)xr;
  float4 v1 = *(const float4*)(xr+4);
  float s = v0.x+v0.y+v0.z+v0.w+v1.x+v1.y+v1.z+v1.w;
  #pragma unroll
  for (int mk=16; mk; mk>>=1) s += __shfl_xor(s, mk);
  float mu = s*(1.0f/256.0f);
  float vv[8] = {v0.x,v0.y,v0.z,v0.w,v1.x,v1.y,v1.z,v1.w};
  float q = 0.f;
  #pragma unroll
  for (int k=0;k<8;k++){ float d = vv[k]-mu; q += d*d; }
  #pragma unroll
  for (int mk=16; mk; mk>>=1) q += __shfl_xor(q, mk);
  float rs = rsqrtf(q*(1.0f/256.0f)+1e-5f);
  short8 o;
  #pragma unroll
  for (int k=0;k<8;k++){
    int d = l32*8+k;
    o[k] = (short)bf16bits((vv[k]-mu)*rs*gamma[p*(LL*DD)+d]+beta[p*(LL*DD)+d]);
  }
  *(short8*)(Y + row*DD + l32*8) = o;
}

// Kw: wq/w1/w2 -> bf16 transposed [pl][N][K]
__global__ __launch_bounds__(256) void wconv_all_kernel(
    const float* __restrict__ wq, const float* __restrict__ w1,
    const float* __restrict__ w2,
    __hip_bfloat16* __restrict__ wqT, __hip_bfloat16* __restrict__ w1T,
    __hip_bfloat16* __restrict__ w2T)
{
  int z = blockIdx.x;
  const float* src; __hip_bfloat16* dst; int K, N, rel;
  if (z < 256)      { src=wq; dst=wqT; K=DD;   N=INNER; rel=z; }
  else if (z < 768) { src=w1; dst=w1T; K=DD;   N=FFD;   rel=z-256; }
  else              { src=w2; dst=w2T; K=FFD;  N=DD;    rel=z-768; }
  int tn = N>>6, tk = K>>6, per = tn*tk;
  int pl = rel/per, r2 = rel%per;
  int n0 = (r2%tn)*64, k0 = (r2/tn)*64;
  __shared__ float t[64][65];
  int tid = threadIdx.x;
  #pragma unroll
  for (int i=0;i<16;i++){
    int idx = i*256+tid;
    int kk = idx>>6, nn = idx&63;
    t[kk][nn] = src[((long)pl*K + k0+kk)*N + n0+nn];
  }
  __syncthreads();
  #pragma unroll
  for (int i=0;i<16;i++){
    int idx = i*256+tid;
    int nn = idx>>6, kk = idx&63;
    dst[((long)pl*N + n0+nn)*K + k0+kk] = __float2bfloat16(t[kk][nn]);
  }
}

// Kqv: qk[l,g][128(pad)][256] (SCALE folded) and vwoT[l,g][256][64], bf16.
// qk[hj][c] = SCALE * sum_d wq[c][h*64+d]*K[j][h*64+d]
// vwoT[c][hj] = sum_d V[j][h*64+d]*wo[h*64+d][c]
__global__ __launch_bounds__(256) void qkvwo_kernel(
    const float* __restrict__ kvk, const float* __restrict__ kvv,
    const __hip_bfloat16* __restrict__ wqT, const float* __restrict__ wo,
    __hip_bfloat16* __restrict__ qkPad, __hip_bfloat16* __restrict__ vwoT)
{
  int z = blockIdx.x;                // l*16 + g
  int l = z>>4, g = z&15;
  int b = g>>2, p = g&3;
  int pl = p*LL + l;
  int c = threadIdx.x;
  __shared__ float kvkL[8][512];
  __shared__ float kvvL[8][512];
  __shared__ float tr[256][66];
  #pragma unroll
  for (int i=0;i<16;i++){
    int idx = i*256 + c;
    int j = idx>>9, d = idx&511;
    long off = ((long)pl*BB + b)*(NT*INNER) + j*INNER + d;
    kvkL[j][d] = kvk[off];
    kvvL[j][d] = kvv[off];
  }
  __syncthreads();
  __hip_bfloat16* qkg = qkPad + (long)z*128*256;
  __hip_bfloat16* vwg = vwoT + (long)z*256*64;
  for (int h=0;h<8;h++){
    float qa[8] = {0,0,0,0,0,0,0,0};
    float va[8] = {0,0,0,0,0,0,0,0};
    for (int d=0;d<64;d++){
      int dd = h*64 + d;
      float wqv = bf2f(*(const unsigned short*)(wqT + ((long)pl*INNER + dd)*DD + c));
      float wov = wo[((long)pl*INNER + dd)*DD + c];
      #pragma unroll
      for (int j=0;j<8;j++){
        qa[j] = fmaf(kvkL[j][dd], wqv, qa[j]);
        va[j] = fmaf(kvvL[j][dd], wov, va[j]);
      }
    }
    #pragma unroll
    for (int j=0;j<8;j++){
      qkg[(h*8+j)*256 + c] = __float2bfloat16(qa[j]*SCALE);
      tr[c][h*8+j] = va[j];
    }
  }
  // zero pad rows 64..127 of qk
  #pragma unroll
  for (int i=0;i<8;i++){
    short8 zz = {0,0,0,0,0,0,0,0};
    *(short8*)(qkg + 64*256 + (i*256 + c)*8) = zz;
  }
  __syncthreads();
  // write vwoT rows (c-major [256][64])
  #pragma unroll
  for (int k8=0;k8<8;k8++){
    short8 o;
    #pragma unroll
    for (int k=0;k<8;k++) o[k] = (short)bf16bits(tr[c][k8*8+k]);
    *(short8*)(vwg + c*64 + k8*8) = o;
  }
}

// K9: MFMA bf16 GEMM, 2-phase double-buffered. Grid (rowTiles, colTiles, g)
template<bool HASBIAS, bool GELU, bool ACCUM, bool BPERG, bool F32OUT>
__global__ __launch_bounds__(256) void mfma_gemm(
    const __hip_bfloat16* __restrict__ A, long astride, int K,
    const __hip_bfloat16* __restrict__ BT, long bpstride,
    const float* __restrict__ bias, int bias_pstride,
    void* __restrict__ Cp, int ldc, long cstride)
{
  int g = blockIdx.z;
  int p = g & 3;
  int pg = BPERG ? g : p;
  const __hip_bfloat16* Ag = A  + (long)g*astride + (long)blockIdx.x*128*K;
  const __hip_bfloat16* Bg = BT + (long)pg*bpstride + (long)blockIdx.y*128*K;
  const float* biasg = HASBIAS ? (bias + (long)p*bias_pstride) : nullptr;

  __shared__ __align__(16) __hip_bfloat16 Asm[2][128*64];
  __shared__ __align__(16) __hip_bfloat16 Bsm[2][128*64];

  int tid = threadIdx.x;
  int w = tid>>6, lane = tid&63;
  int wr = w>>1, wc = w&1;
  int lr = lane>>4, lc = lane&15;
  int ldsbase = tid & ~63;

  const __hip_bfloat16* aseg[4];
  const __hip_bfloat16* bseg[4];
  #pragma unroll
  for (int i=0;i<4;i++){
    int seg = i*256 + tid;
    int r = seg>>3, sl = seg&7;
    int sg = sl ^ (r&7);
    aseg[i] = Ag + (long)r*K + sg*8;
    bseg[i] = Bg + (long)r*K + sg*8;
  }

  f32x4 acc[4][4] = {};
  int nt = K >> 6;

  #define STAGE(buf) do { \
    _Pragma("unroll") \
    for (int i_=0;i_<4;i_++) \
      GLD_LDS16(aseg[i_], &Asm[buf][(i_*256 + ldsbase)*8]); \
    _Pragma("unroll") \
    for (int i_=0;i_<4;i_++) \
      GLD_LDS16(bseg[i_], &Bsm[buf][(i_*256 + ldsbase)*8]); \
    _Pragma("unroll") \
    for (int i_=0;i_<4;i_++){ aseg[i_] += 64; bseg[i_] += 64; } \
  } while(0)

  STAGE(0);
  asm volatile("s_waitcnt vmcnt(0)" ::: "memory");
  __syncthreads();

  for (int t=0; t<nt; t++){
    int cur = t & 1;
    if (t+1 < nt) STAGE(cur^1);
    #pragma unroll
    for (int kc=0;kc<2;kc++){
      bf16x8 af[4], bfr[4];
      #pragma unroll
      for (int mi=0;mi<4;mi++){
        int r = wr*64 + mi*16 + lc;
        int s = kc*4 + lr;
        af[mi] = *(const bf16x8*)(&Asm[cur][r*64 + (s ^ (r&7))*8]);
      }
      #pragma unroll
      for (int ni=0;ni<4;ni++){
        int r = wc*64 + ni*16 + lc;
        int s = kc*4 + lr;
        bfr[ni] = *(const bf16x8*)(&Bsm[cur][r*64 + (s ^ (r&7))*8]);
      }
      #pragma unroll
      for (int mi=0;mi<4;mi++)
        #pragma unroll
        for (int ni=0;ni<4;ni++)
          acc[mi][ni] = __builtin_amdgcn_mfma_f32_16x16x32_bf16(af[mi], bfr[ni], acc[mi][ni], 0, 0, 0);
    }
    if (t+1 < nt) asm volatile("s_waitcnt vmcnt(0)" ::: "memory");
    __syncthreads();
  }
  #undef STAGE

  if (ACCUM || F32OUT){
    float* Cg = (float*)Cp + (long)g*cstride;
    #pragma unroll
    for (int ni=0;ni<4;ni++){
      int col = blockIdx.y*128 + wc*64 + ni*16 + lc;
      float bv = HASBIAS ? biasg[col] : 0.0f;
      #pragma unroll
      for (int mi=0;mi<4;mi++){
        int row = blockIdx.x*128 + wr*64 + mi*16 + lr*4;
        #pragma unroll
        for (int j=0;j<4;j++){
          float v = acc[mi][ni][j] + bv;
          if (GELU) v = gelu_f(v);
          if (ACCUM) Cg[(long)(row+j)*ldc + col] += v;
          else       Cg[(long)(row+j)*ldc + col] = v;
        }
      }
    }
  } else {
    __hip_bfloat16* Cg = (__hip_bfloat16*)Cp + (long)g*cstride;
    #pragma unroll
    for (int ni=0;ni<4;ni++){
      int col = blockIdx.y*128 + wc*64 + ni*16 + lc;
      float bv = HASBIAS ? biasg[col] : 0.0f;
      #pragma unroll
      for (int mi=0;mi<4;mi++){
        int row = blockIdx.x*128 + wr*64 + mi*16 + lr*4;
        #pragma unroll
        for (int j=0;j<4;j++){
          float v = acc[mi][ni][j] + bv;
          if (GELU) v = gelu_f(v);
          Cg[(long)(row+j)*ldc + col] = __float2bfloat16(v);
        }
      }
    }
  }
}

// K10: per-head softmax over 8 slots; logits fp32 (16384x128) -> P bf16 (16384x64)
__global__ __launch_bounds__(256) void softmax8_kernel(
    const float* __restrict__ logits, __hip_bfloat16* __restrict__ P)
{
  int t = blockIdx.x*32 + (threadIdx.x>>3);
  int h = threadIdx.x&7;
  const float* lr = logits + (long)t*128 + h*8;
  float4 a0 = *(const float4*)lr;
  float4 a1 = *(const float4*)(lr+4);
  float lgv[8] = {a0.x,a0.y,a0.z,a0.w,a1.x,a1.y,a1.z,a1.w};
  float mx = -1e30f;
  #pragma unroll
  for (int j=0;j<8;j++) mx = fmaxf(mx, lgv[j]);
  float e[8], s = 0.f;
  #pragma unroll
  for (int j=0;j<8;j++){ e[j] = __expf(lgv[j]-mx); s += e[j]; }
  float inv = 1.0f/s;
  short8 o;
  #pragma unroll
  for (int j=0;j<8;j++) o[j] = (short)bf16bits(e[j]*inv);
  *(short8*)(P + (long)t*64 + h*8) = o;
}

// K11: final scale+LN+scatter
__global__ __launch_bounds__(256) void final_kernel(
    const float* __restrict__ Xc, const int* __restrict__ cidx,
    const float* __restrict__ pw, const float* __restrict__ fln_g,
    const float* __restrict__ fln_b, float* __restrict__ out)
{
  long slot = (long)blockIdx.x*8 + (threadIdx.x>>5);
  int l32 = threadIdx.x & 31;
  int b = (int)(slot>>12);
  int p = (int)((slot>>10)&3);
  int i = cidx[slot];
  float pwv = pw[b*PP+p];
  const float* xr = Xc + slot*DD + l32*8;
  float4 v0 = *(const float4*)xr;
  float4 v1 = *(const float4*)(xr+4);
  float vv[8] = {v0.x,v0.y,v0.z,v0.w,v1.x,v1.y,v1.z,v1.w};
  #pragma unroll
  for (int k=0;k<8;k++) vv[k] *= pwv;
  float s = 0.f;
  #pragma unroll
  for (int k=0;k<8;k++) s += vv[k];
  #pragma unroll
  for (int mk=16; mk; mk>>=1) s += __shfl_xor(s, mk);
  float mu = s*(1.0f/256.0f);
  float q = 0.f;
  #pragma unroll
  for (int k=0;k<8;k++){ float d = vv[k]-mu; q += d*d; }
  #pragma unroll
  for (int mk=16; mk; mk>>=1) q += __shfl_xor(q, mk);
  float rs = rsqrtf(q*(1.0f/256.0f)+1e-5f);
  float* op = out + ((long)b*NN+i)*DD + l32*8;
  float4 o0, o1;
  o0.x = (vv[0]-mu)*rs*fln_g[l32*8+0]+fln_b[l32*8+0];
  o0.y = (vv[1]-mu)*rs*fln_g[l32*8+1]+fln_b[l32*8+1];
  o0.z = (vv[2]-mu)*rs*fln_g[l32*8+2]+fln_b[l32*8+2];
  o0.w = (vv[3]-mu)*rs*fln_g[l32*8+3]+fln_b[l32*8+3];
  o1.x = (vv[4]-mu)*rs*fln_g[l32*8+4]+fln_b[l32*8+4];
  o1.y = (vv[5]-mu)*rs*fln_g[l32*8+5]+fln_b[l32*8+5];
  o1.z = (vv[6]-mu)*rs*fln_g[l32*8+6]+fln_b[l32*8+6];
  o1.w = (vv[7]-mu)*rs*fln_g[l32*8+7]+fln_b[l32*8+7];
  *(float4*)op = o0;
  *(float4*)(op+4) = o1;
}

extern "C" void kernel_launch(void* const* d_in, const int* in_sizes, int n_in,
                              void* d_out, int out_size, void* d_ws, size_t ws_size,
                              hipStream_t stream)
{
  (void)in_sizes; (void)n_in; (void)out_size; (void)ws_size;
  const float* x     =(const float*)d_in[0];
  const float* m     =(const float*)d_in[1];
  const float* proj_w=(const float*)d_in[2];
  const float* proj_b=(const float*)d_in[3];
  const float* lnp_g =(const float*)d_in[4];
  const float* lnp_b =(const float*)d_in[5];
  const float* sq_w  =(const float*)d_in[6];
  const float* sq_b  =(const float*)d_in[7];
  const float* sk_w  =(const float*)d_in[8];
  const float* sk_b  =(const float*)d_in[9];
  const float* sv_w  =(const float*)d_in[10];
  const float* sv_b  =(const float*)d_in[11];
  const float* an_g  =(const float*)d_in[12];
  const float* an_b  =(const float*)d_in[13];
  const float* wq    =(const float*)d_in[14];
  const float* wk    =(const float*)d_in[15];
  const float* wv    =(const float*)d_in[16];
  const float* wo    =(const float*)d_in[17];
  const float* wo_b  =(const float*)d_in[18];
  const float* fn_g  =(const float*)d_in[19];
  const float* fn_b  =(const float*)d_in[20];
  const float* w1    =(const float*)d_in[21];
  const float* b1    =(const float*)d_in[22];
  const float* w2    =(const float*)d_in[23];
  const float* b2    =(const float*)d_in[24];
  const float* fln_g =(const float*)d_in[25];
  const float* fln_b =(const float*)d_in[26];
  float* out = (float*)d_out;

  float* ws = (float*)d_ws;
  float* tokens  = ws;  ws += 4194304;  // 16 MB (also start of actF 32MB span)
  float* logitsF = ws;  ws += 2097152;  // 8 MB fp32 16384x128
  float* Pbuff   = ws;  ws += 524288;   // 2 MB bf16 16384x64
  ws += 1572864;                        // 6 MB spill to complete actF 32MB span
  float* Xc      = ws;  ws += 4194304;  // fp32 residual
  float* actAf   = ws;  ws += 2097152;  // bf16 16384x256
  float* wqTf    = ws;  ws += 524288;
  float* w1Tf    = ws;  ws += 1048576;
  float* w2Tf    = ws;  ws += 1048576;
  float* qkPadf  = ws;  ws += 524288;   // bf16 [2][16][128][256]
  float* vwoTf   = ws;  ws += 262144;   // bf16 [2][16][256][64]
  float* kvk     = ws;  ws += 131072;
  float* kvv     = ws;  ws += 131072;
  float* kk2     = ws;  ws += 8192;
  float* kb      = ws;  ws += 32;
  float* vsc     = ws;  ws += 64;
  float* scores  = ws;  ws += 16384;
  float* pw      = ws;  ws += 16;
  int* rank      = (int*)ws;  ws += 16384;
  int* cidx      = (int*)ws;  ws += 16384;

  __hip_bfloat16* actA  = (__hip_bfloat16*)actAf;
  __hip_bfloat16* actF  = (__hip_bfloat16*)tokens;   // 16384x1024 bf16 span
  __hip_bfloat16* Pb    = (__hip_bfloat16*)Pbuff;
  __hip_bfloat16* wqT   = (__hip_bfloat16*)wqTf;
  __hip_bfloat16* w1T   = (__hip_bfloat16*)w1Tf;
  __hip_bfloat16* w2T   = (__hip_bfloat16*)w2Tf;
  __hip_bfloat16* qkPad = (__hip_bfloat16*)qkPadf;
  __hip_bfloat16* vwoT  = (__hip_bfloat16*)vwoTf;

  hipMemsetAsync(rank, 0, BB*NN*sizeof(int), stream);
  scorer_kk2_kernel<<<32,256,0,stream>>>(m, sk_w, sk_b, sv_w, sv_b, sq_w, sq_b,
                                         kk2, kb, vsc);
  proj_ln_score_kernel<<<1024,256,0,stream>>>(x, proj_w, proj_b, lnp_g, lnp_b,
                                              kk2, kb, vsc, tokens, scores);
  rank_partial_kernel<<<1024,256,0,stream>>>(scores, rank);
  rank_finalize_kernel<<<64,256,0,stream>>>(rank, cidx);
  pscore_pw_kernel<<<1,1024,0,stream>>>(scores, cidx, pw);
  kv_kernel<<<256,512,0,stream>>>(m, an_g, an_b, wk, wv, kvk, kvv);
  wconv_all_kernel<<<1280,256,0,stream>>>(wq, w1, w2, wqT, w1T, w2T);
  qkvwo_kernel<<<32,256,0,stream>>>(kvk, kvv, wqT, wo, qkPad, vwoT);
  gather_ln_kernel<<<2048,256,0,stream>>>(tokens, cidx, Xc, actA, an_g, an_b);

  for (int l=0;l<LL;l++){
    if (l > 0)
      ln_rows_kernel<<<2048,256,0,stream>>>(Xc, actA, an_g + l*DD, an_b + l*DD);
    // logits = xn @ qk^T  (1024x128(pad)x256 per group) -> fp32
    mfma_gemm<false,false,false,true,true><<<dim3(8,1,16),256,0,stream>>>(
        actA, (long)SS*DD, DD, qkPad + (long)l*16*128*256, (long)128*256,
        nullptr, 0, logitsF, 128, (long)SS*128);
    softmax8_kernel<<<512,256,0,stream>>>(logitsF, Pb);
    // Xc += P @ vwoT^T + wo_b  (1024x256x64 per group)
    mfma_gemm<true,false,true,true,false><<<dim3(8,2,16),256,0,stream>>>(
        Pb, (long)SS*64, 64, vwoT + (long)l*16*256*64, (long)256*64,
        wo_b + l*DD, LL*DD, Xc, DD, (long)SS*DD);
    ln_rows_kernel<<<2048,256,0,stream>>>(Xc, actA, fn_g + l*DD, fn_b + l*DD);
    // F = gelu(h @ w1 + b1)
    mfma_gemm<true,true,false,false,false><<<dim3(8,8,16),256,0,stream>>>(
        actA, (long)SS*DD, DD, w1T + (long)l*FFD*DD, (long)LL*FFD*DD,
        b1 + l*FFD, LL*FFD, actF, FFD, (long)SS*FFD);
    // Xc += F @ w2 + b2
    mfma_gemm<true,false,true,false,false><<<dim3(8,2,16),256,0,stream>>>(
        actF, (long)SS*FFD, FFD, w2T + (long)l*DD*FFD, (long)LL*DD*FFD,
        b2 + l*DD, LL*DD, Xc, DD, (long)SS*DD);
  }
  final_kernel<<<2048,256,0,stream>>>(Xc, cidx, pw, fln_g, fln_b, out);
}

// Round 10
// 325.097 us; speedup vs baseline: 1.2179x; 1.2179x over previous
//
#include <hip/hip_runtime.h>
#include <hip/hip_bf16.h>
#include <math.h>

// Problem constants
#define BB 4
#define CC 128
#define NN 4096      // H*W
#define DD 256
#define INNER 512
#define FFD 1024
#define PP 4
#define LL 2
#define NT 8
#define SS 1024      // NN/PP
#define SCALE 0.0625f // 1/sqrt(256)

typedef __attribute__((ext_vector_type(8))) short bf16x8;
typedef __attribute__((ext_vector_type(8))) short short8;
typedef __attribute__((ext_vector_type(4))) float f32x4;

#define GLD_LDS16(g, l) __builtin_amdgcn_global_load_lds( \
    (const __attribute__((address_space(1))) void*)(g), \
    (__attribute__((address_space(3))) void*)(l), 16, 0, 0)

template<int NW>
__device__ inline float block_sum(float v, float* sbuf){
  #pragma unroll
  for (int mk=32; mk; mk>>=1) v += __shfl_xor(v, mk);
  int w = threadIdx.x>>6;
  if ((threadIdx.x&63)==0) sbuf[w]=v;
  __syncthreads();
  float r = 0.f;
  #pragma unroll
  for (int k=0;k<NW;k++) r += sbuf[k];
  __syncthreads();
  return r;
}

__device__ inline unsigned short bf16bits(float v){
  __hip_bfloat16 t = __float2bfloat16(v);
  unsigned short u;
  __builtin_memcpy(&u, &t, 2);
  return u;
}
__device__ inline float bf2f(unsigned short u){
  unsigned int x = ((unsigned int)u)<<16;
  float f;
  __builtin_memcpy(&f, &x, 4);
  return f;
}

// fast GELU: erf via Abramowitz-Stegun 7.1.26 (|eps| <= 1.5e-7)
__device__ inline float gelu_f(float x){
  float z  = x * 0.70710678118654752440f;
  float az = fabsf(z);
  float t  = 1.0f / (1.0f + 0.3275911f*az);
  float y  = t*(0.254829592f + t*(-0.284496736f + t*(1.421413741f +
             t*(-1.453152027f + t*1.061405429f))));
  float erfv = 1.0f - y*__expf(-az*az);
  erfv = (z < 0.0f) ? -erfv : erfv;
  return 0.5f*x*(1.0f+erfv);
}

// K2: merged scorer: ksc (LDS only), then kk2/kb/vsc outputs
__global__ __launch_bounds__(256) void scorer_kk2_kernel(
    const float* __restrict__ m, const float* __restrict__ sk_w,
    const float* __restrict__ sk_b, const float* __restrict__ sv_w,
    const float* __restrict__ sv_b, const float* __restrict__ sq_w,
    const float* __restrict__ sq_b,
    float* __restrict__ kk2, float* __restrict__ kb, float* __restrict__ vsc)
{
  int bj = blockIdx.x;               // B*NT = 32
  int d = threadIdx.x;
  __shared__ float ms[256];
  __shared__ float ks[256];
  __shared__ float sbuf[4];
  ms[d] = m[bj*DD + d];
  __syncthreads();
  float acc=0.f;
  for(int c=0;c<DD;c++) acc = fmaf(ms[c], sk_w[c*DD + d], acc);
  ks[d] = acc + sk_b[d];
  float sv = block_sum<4>(ms[d]*sv_w[d], sbuf);
  if(d==0) vsc[bj] = sv + sv_b[0];
  __syncthreads();
  const float* wr = sq_w + (long)d*DD;
  float a2 = 0.f;
  for (int c=0; c<DD; c+=4){
    float4 wv = *(const float4*)(wr + c);
    a2 = fmaf(wv.x, ks[c+0], fmaf(wv.y, ks[c+1], fmaf(wv.z, ks[c+2], fmaf(wv.w, ks[c+3], a2))));
  }
  kk2[bj*DD + d] = a2;
  float kbv = block_sum<4>(sq_b[d]*ks[d], sbuf);
  if (d==0) kb[bj] = kbv;
}

// K1: tokens = LN(conv1x1(x)) AND scores via factored scorer. 16 tokens/block.
__global__ __launch_bounds__(256) void proj_ln_score_kernel(
    const float* __restrict__ x, const float* __restrict__ proj_w,
    const float* __restrict__ proj_b, const float* __restrict__ lnp_g,
    const float* __restrict__ lnp_b, const float* __restrict__ kk2,
    const float* __restrict__ kb, const float* __restrict__ vsc,
    float* __restrict__ tokens, float* __restrict__ scores)
{
  int b  = blockIdx.x >> 8;
  int n0 = (blockIdx.x & 255) * 16;
  int tid = threadIdx.x;
  __shared__ float xs[16][132];
  __shared__ float ys[16][260];
  __shared__ float kj[8][260];
  __shared__ float kbs[8], vs[8];
  __shared__ float mu_s[16], rs_s[16];
  __shared__ float lg[16][8];
  #pragma unroll
  for (int i=0;i<8;i++){
    int l = tid + i*256;
    int t = l & 15, c = l >> 4;
    xs[t][c] = x[(long)(b*CC + c)*NN + n0 + t];
  }
  #pragma unroll
  for (int i=0;i<8;i++){
    int idx = i*256 + tid;
    int r = idx >> 8, c = idx & 255;
    kj[r][c] = kk2[(b*NT + r)*DD + c];
  }
  if (tid < 8){ kbs[tid] = kb[b*NT+tid]; vs[tid] = vsc[b*NT+tid]; }
  __syncthreads();
  float acc[16];
  #pragma unroll
  for (int t=0;t<16;t++) acc[t]=0.f;
  for (int c0=0;c0<CC;c0+=4){
    float w0 = proj_w[(c0+0)*DD + tid];
    float w1_ = proj_w[(c0+1)*DD + tid];
    float w2_ = proj_w[(c0+2)*DD + tid];
    float w3_ = proj_w[(c0+3)*DD + tid];
    #pragma unroll
    for (int t=0;t<16;t++){
      float4 xv = *(const float4*)&xs[t][c0];
      acc[t] = fmaf(xv.x,w0,fmaf(xv.y,w1_,fmaf(xv.z,w2_,fmaf(xv.w,w3_,acc[t]))));
    }
  }
  float pb = proj_b[tid];
  #pragma unroll
  for (int t=0;t<16;t++) ys[t][tid] = acc[t] + pb;
  __syncthreads();
  int w = tid>>6, lane = tid&63;
  for (int k=0;k<4;k++){
    int t = w*4+k;
    float s = ys[t][lane] + ys[t][lane+64] + ys[t][lane+128] + ys[t][lane+192];
    #pragma unroll
    for (int mk=32; mk; mk>>=1) s += __shfl_xor(s, mk);
    float mu = s*(1.0f/256.0f);
    float d0=ys[t][lane]-mu, d1=ys[t][lane+64]-mu, d2=ys[t][lane+128]-mu, d3=ys[t][lane+192]-mu;
    float q = d0*d0+d1*d1+d2*d2+d3*d3;
    #pragma unroll
    for (int mk=32; mk; mk>>=1) q += __shfl_xor(q, mk);
    if (lane==0){ mu_s[t]=mu; rs_s[t]=rsqrtf(q*(1.0f/256.0f)+1e-5f); }
  }
  __syncthreads();
  float g = lnp_g[tid], be = lnp_b[tid];
  #pragma unroll
  for (int t=0;t<16;t++){
    float nv = (ys[t][tid]-mu_s[t])*rs_s[t]*g + be;
    tokens[((long)(b*NN + n0 + t))*DD + tid] = nv;
    ys[t][tid] = nv;
  }
  __syncthreads();
  if (tid < 128){
    int t = tid>>3, j = tid&7;
    float a2 = 0.f;
    for (int c0=0;c0<DD;c0+=4){
      float4 tv = *(const float4*)&ys[t][c0];
      float4 kv = *(const float4*)&kj[j][c0];
      a2 = fmaf(tv.x,kv.x,fmaf(tv.y,kv.y,fmaf(tv.z,kv.z,fmaf(tv.w,kv.w,a2))));
    }
    lg[t][j] = (a2 + kbs[j]) * SCALE;
  }
  __syncthreads();
  if (tid < 16){
    float mx=-1e30f;
    #pragma unroll
    for(int j=0;j<NT;j++) mx=fmaxf(mx,lg[tid][j]);
    float s=0.f, sc=0.f;
    #pragma unroll
    for(int j=0;j<NT;j++){ float e=__expf(lg[tid][j]-mx); s+=e; sc+=e*vs[j]; }
    scores[b*NN + n0 + tid] = sc/s;
  }
}

// K3a: partial ranks
__global__ __launch_bounds__(256) void rank_partial_kernel(
    const float* __restrict__ scores, int* __restrict__ rank)
{
  int b  = blockIdx.x >> 8;
  int it = (blockIdx.x >> 4) & 15;
  int jt = blockIdx.x & 15;
  int i = it*256 + threadIdx.x;
  float si = scores[b*NN + i];
  __shared__ float ss[256];
  ss[threadIdx.x] = scores[b*NN + jt*256 + threadIdx.x];
  __syncthreads();
  int jbase = jt*256;
  int cnt = 0;
  #pragma unroll 4
  for (int j=0;j<256;j++){
    float sj = ss[j];
    cnt += (sj > si) || (sj == si && (jbase+j) < i);
  }
  atomicAdd(&rank[b*NN+i], cnt);
}

// K3b
__global__ __launch_bounds__(256) void rank_finalize_kernel(
    const int* __restrict__ rank, int* __restrict__ cidx)
{
  int b = blockIdx.x >> 4;
  int i = (blockIdx.x & 15)*256 + threadIdx.x;
  int rk = rank[b*NN + i];
  int p = rk >> 10;
  cidx[(b*PP + p)*SS + (rk & (SS-1))] = i;
}

// K4
__global__ __launch_bounds__(1024) void pscore_pw_kernel(
    const float* __restrict__ scores, const int* __restrict__ cidx,
    float* __restrict__ pw)
{
  __shared__ float ps[16];
  int wv = threadIdx.x>>6;
  int lane = threadIdx.x&63;
  int b = wv>>2;
  float acc=0.f;
  for (int s=lane; s<SS; s+=64) acc += scores[b*NN + cidx[wv*SS + s]];
  #pragma unroll
  for (int mk=32; mk; mk>>=1) acc += __shfl_xor(acc, mk);
  if (lane==0) ps[wv] = acc*(1.0f/(float)SS);
  __syncthreads();
  if (threadIdx.x < BB){
    int bb = threadIdx.x;
    float mx=-1e30f;
    #pragma unroll
    for(int p=0;p<PP;p++) mx=fmaxf(mx,ps[bb*PP+p]);
    float s=0.f,e[PP];
    #pragma unroll
    for(int p=0;p<PP;p++){ e[p]=__expf(ps[bb*PP+p]-mx); s+=e[p]; }
    #pragma unroll
    for(int p=0;p<PP;p++) pw[bb*PP+p]=e[p]/s;
  }
}

// K6: gather + LN(an[p,0]) fused
__global__ __launch_bounds__(256) void gather_ln_kernel(
    const float* __restrict__ tokens, const int* __restrict__ cidx,
    float* __restrict__ Xc, __hip_bfloat16* __restrict__ Y,
    const float* __restrict__ gamma, const float* __restrict__ beta)
{
  long slot = (long)blockIdx.x*8 + (threadIdx.x>>5);
  int l32 = threadIdx.x & 31;
  int b = (int)(slot >> 12);
  int p = (int)((slot>>10)&3);
  int i = cidx[slot];
  const float* src = tokens + ((long)b*NN + i)*DD + l32*8;
  float4 v0 = *(const float4*)src;
  float4 v1 = *(const float4*)(src+4);
  *(float4*)(Xc + slot*DD + l32*8) = v0;
  *(float4*)(Xc + slot*DD + l32*8 + 4) = v1;
  float s = v0.x+v0.y+v0.z+v0.w+v1.x+v1.y+v1.z+v1.w;
  #pragma unroll
  for (int mk=16; mk; mk>>=1) s += __shfl_xor(s, mk);
  float mu = s*(1.0f/256.0f);
  float vv[8] = {v0.x,v0.y,v0.z,v0.w,v1.x,v1.y,v1.z,v1.w};
  float q = 0.f;
  #pragma unroll
  for (int k=0;k<8;k++){ float d = vv[k]-mu; q += d*d; }
  #pragma unroll
  for (int mk=16; mk; mk>>=1) q += __shfl_xor(q, mk);
  float rs = rsqrtf(q*(1.0f/256.0f)+1e-5f);
  short8 o;
  #pragma unroll
  for (int k=0;k<8;k++){
    int d = l32*8+k;
    o[k] = (short)bf16bits((vv[k]-mu)*rs*gamma[p*(LL*DD)+d]+beta[p*(LL*DD)+d]);
  }
  *(short8*)(Y + slot*DD + l32*8) = o;
}

// K7: decoder K/V precompute (plain layout)
__global__ __launch_bounds__(512) void kv_kernel(
    const float* __restrict__ m, const float* __restrict__ an_g,
    const float* __restrict__ an_b, const float* __restrict__ wk,
    const float* __restrict__ wv, float* __restrict__ kvk, float* __restrict__ kvv)
{
  int idx = blockIdx.x;              // (pl*B + b)*NT + j, grid 256
  int j = idx & 7, b = (idx>>3)&3, pl = idx>>5;
  int tid = threadIdx.x;
  __shared__ float mn[256];
  __shared__ float sbuf[8];
  float v = (tid<256) ? m[(b*NT+j)*DD + tid] : 0.0f;
  float s = block_sum<8>(v, sbuf);
  float mu = s*(1.0f/256.0f);
  float dv = (tid<256)? v-mu : 0.0f;
  float q = block_sum<8>(dv*dv, sbuf);
  float rs = rsqrtf(q*(1.0f/256.0f)+1e-5f);
  if (tid<256) mn[tid] = dv*rs*an_g[pl*DD+tid] + an_b[pl*DD+tid];
  __syncthreads();
  float ka=0.f, va=0.f;
  for (int c=0;c<DD;c++){
    float mc = mn[c];
    ka = fmaf(mc, wk[((long)pl*DD + c)*INNER + tid], ka);
    va = fmaf(mc, wv[((long)pl*DD + c)*INNER + tid], va);
  }
  long off = ((long)pl*BB + b)*(NT*INNER) + j*INNER + tid;
  kvk[off]=ka; kvv[off]=va;
}

// K8: rowwise LN -> bf16
__global__ __launch_bounds__(256) void ln_rows_kernel(
    const float* __restrict__ X, __hip_bfloat16* __restrict__ Y,
    const float* __restrict__ gamma, const float* __restrict__ beta)
{
  long row = (long)blockIdx.x*8 + (threadIdx.x>>5);
  int l32 = threadIdx.x & 31;
  int p = (int)((row>>10)&3);
  const float* xr = X + row*DD + l32*8;
  float4 v0 = *(const float4*)xr;
  float4 v1 = *(const float4*)(xr+4);
  float s = v0.x+v0.y+v0.z+v0.w+v1.x+v1.y+v1.z+v1.w;
  #pragma unroll
  for (int mk=16; mk; mk>>=1) s += __shfl_xor(s, mk);
  float mu = s*(1.0f/256.0f);
  float vv[8] = {v0.x,v0.y,v0.z,v0.w,v1.x,v1.y,v1.z,v1.w};
  float q = 0.f;
  #pragma unroll
  for (int k=0;k<8;k++){ float d = vv[k]-mu; q += d*d; }
  #pragma unroll
  for (int mk=16; mk; mk>>=1) q += __shfl_xor(q, mk);
  float rs = rsqrtf(q*(1.0f/256.0f)+1e-5f);
  short8 o;
  #pragma unroll
  for (int k=0;k<8;k++){
    int d = l32*8+k;
    o[k] = (short)bf16bits((vv[k]-mu)*rs*gamma[p*(LL*DD)+d]+beta[p*(LL*DD)+d]);
  }
  *(short8*)(Y + row*DD + l32*8) = o;
}

// Kw: wq/w1/w2 -> bf16 transposed [pl][N][K]
__global__ __launch_bounds__(256) void wconv_all_kernel(
    const float* __restrict__ wq, const float* __restrict__ w1,
    const float* __restrict__ w2,
    __hip_bfloat16* __restrict__ wqT, __hip_bfloat16* __restrict__ w1T,
    __hip_bfloat16* __restrict__ w2T)
{
  int z = blockIdx.x;
  const float* src; __hip_bfloat16* dst; int K, N, rel;
  if (z < 256)      { src=wq; dst=wqT; K=DD;   N=INNER; rel=z; }
  else if (z < 768) { src=w1; dst=w1T; K=DD;   N=FFD;   rel=z-256; }
  else              { src=w2; dst=w2T; K=FFD;  N=DD;    rel=z-768; }
  int tn = N>>6, tk = K>>6, per = tn*tk;
  int pl = rel/per, r2 = rel%per;
  int n0 = (r2%tn)*64, k0 = (r2/tn)*64;
  __shared__ float t[64][65];
  int tid = threadIdx.x;
  #pragma unroll
  for (int i=0;i<16;i++){
    int idx = i*256+tid;
    int kk = idx>>6, nn = idx&63;
    t[kk][nn] = src[((long)pl*K + k0+kk)*N + n0+nn];
  }
  __syncthreads();
  #pragma unroll
  for (int i=0;i<16;i++){
    int idx = i*256+tid;
    int nn = idx>>6, kk = idx&63;
    dst[((long)pl*N + n0+nn)*K + k0+kk] = __float2bfloat16(t[kk][nn]);
  }
}

// Kqv: per-(z,head) block: qk rows h*8..h*8+7 (SCALE folded) + vwoT cols h*8..+7
// 256 blocks, 4 KB LDS -> latency-hiding occupancy (was: 32 blocks, 100 KB LDS)
__global__ __launch_bounds__(256) void qkvwo_kernel(
    const float* __restrict__ kvk, const float* __restrict__ kvv,
    const __hip_bfloat16* __restrict__ wqT, const float* __restrict__ wo,
    __hip_bfloat16* __restrict__ qkPad, __hip_bfloat16* __restrict__ vwoT)
{
  int zz = blockIdx.x;               // z*8 + h
  int z = zz>>3, h = zz&7;
  int l = z>>4, g = z&15;
  int b = g>>2, p = g&3;
  int pl = p*LL + l;
  int c = threadIdx.x;
  __shared__ float kL[8][64];
  __shared__ float vL[8][64];
  {
    int j0 = c>>6, d0 = c&63;
    long off = ((long)pl*BB + b)*(NT*INNER) + h*64 + d0;
    kL[j0][d0]   = kvk[off + j0*INNER];
    vL[j0][d0]   = kvv[off + j0*INNER];
    kL[j0+4][d0] = kvk[off + (j0+4)*INNER];
    vL[j0+4][d0] = kvv[off + (j0+4)*INNER];
  }
  __syncthreads();
  float qa[8] = {0,0,0,0,0,0,0,0};
  float va[8] = {0,0,0,0,0,0,0,0};
  const __hip_bfloat16* wqp = wqT + ((long)pl*INNER + h*64)*DD + c;
  const float* wop = wo + ((long)pl*INNER + h*64)*DD + c;
  for (int d=0; d<64; d++){
    float wqv = bf2f(*(const unsigned short*)(wqp + (long)d*DD));
    float wov = wop[(long)d*DD];
    #pragma unroll
    for (int j=0;j<8;j++){
      qa[j] = fmaf(kL[j][d], wqv, qa[j]);
      va[j] = fmaf(vL[j][d], wov, va[j]);
    }
  }
  __hip_bfloat16* qkg = qkPad + (long)z*128*256;
  __hip_bfloat16* vwg = vwoT + (long)z*256*64;
  #pragma unroll
  for (int j=0;j<8;j++)
    qkg[(h*8+j)*256 + c] = __float2bfloat16(qa[j]*SCALE);
  short8 o;
  #pragma unroll
  for (int j=0;j<8;j++) o[j] = (short)bf16bits(va[j]);
  *(short8*)(vwg + c*64 + h*8) = o;
  // zero pad: block h zeros qk rows 64+h*8 .. 64+h*8+7
  unsigned short zu = 0;
  __hip_bfloat16 zb;
  __builtin_memcpy(&zb, &zu, 2);
  #pragma unroll
  for (int k=0;k<8;k++)
    qkg[(64 + h*8 + k)*256 + c] = zb;
}

// K9: MFMA bf16 GEMM, 2-phase double-buffered. Grid (rowTiles, colTiles, g)
template<bool HASBIAS, bool GELU, bool ACCUM, bool BPERG, bool F32OUT>
__global__ __launch_bounds__(256) void mfma_gemm(
    const __hip_bfloat16* __restrict__ A, long astride, int K,
    const __hip_bfloat16* __restrict__ BT, long bpstride,
    const float* __restrict__ bias, int bias_pstride,
    void* __restrict__ Cp, int ldc, long cstride)
{
  int g = blockIdx.z;
  int p = g & 3;
  int pg = BPERG ? g : p;
  const __hip_bfloat16* Ag = A  + (long)g*astride + (long)blockIdx.x*128*K;
  const __hip_bfloat16* Bg = BT + (long)pg*bpstride + (long)blockIdx.y*128*K;
  const float* biasg = HASBIAS ? (bias + (long)p*bias_pstride) : nullptr;

  __shared__ __align__(16) __hip_bfloat16 Asm[2][128*64];
  __shared__ __align__(16) __hip_bfloat16 Bsm[2][128*64];

  int tid = threadIdx.x;
  int w = tid>>6, lane = tid&63;
  int wr = w>>1, wc = w&1;
  int lr = lane>>4, lc = lane&15;
  int ldsbase = tid & ~63;

  const __hip_bfloat16* aseg[4];
  const __hip_bfloat16* bseg[4];
  #pragma unroll
  for (int i=0;i<4;i++){
    int seg = i*256 + tid;
    int r = seg>>3, sl = seg&7;
    int sg = sl ^ (r&7);
    aseg[i] = Ag + (long)r*K + sg*8;
    bseg[i] = Bg + (long)r*K + sg*8;
  }

  f32x4 acc[4][4] = {};
  int nt = K >> 6;

  #define STAGE(buf) do { \
    _Pragma("unroll") \
    for (int i_=0;i_<4;i_++) \
      GLD_LDS16(aseg[i_], &Asm[buf][(i_*256 + ldsbase)*8]); \
    _Pragma("unroll") \
    for (int i_=0;i_<4;i_++) \
      GLD_LDS16(bseg[i_], &Bsm[buf][(i_*256 + ldsbase)*8]); \
    _Pragma("unroll") \
    for (int i_=0;i_<4;i_++){ aseg[i_] += 64; bseg[i_] += 64; } \
  } while(0)

  STAGE(0);
  asm volatile("s_waitcnt vmcnt(0)" ::: "memory");
  __syncthreads();

  for (int t=0; t<nt; t++){
    int cur = t & 1;
    if (t+1 < nt) STAGE(cur^1);
    #pragma unroll
    for (int kc=0;kc<2;kc++){
      bf16x8 af[4], bfr[4];
      #pragma unroll
      for (int mi=0;mi<4;mi++){
        int r = wr*64 + mi*16 + lc;
        int s = kc*4 + lr;
        af[mi] = *(const bf16x8*)(&Asm[cur][r*64 + (s ^ (r&7))*8]);
      }
      #pragma unroll
      for (int ni=0;ni<4;ni++){
        int r = wc*64 + ni*16 + lc;
        int s = kc*4 + lr;
        bfr[ni] = *(const bf16x8*)(&Bsm[cur][r*64 + (s ^ (r&7))*8]);
      }
      #pragma unroll
      for (int mi=0;mi<4;mi++)
        #pragma unroll
        for (int ni=0;ni<4;ni++)
          acc[mi][ni] = __builtin_amdgcn_mfma_f32_16x16x32_bf16(af[mi], bfr[ni], acc[mi][ni], 0, 0, 0);
    }
    if (t+1 < nt) asm volatile("s_waitcnt vmcnt(0)" ::: "memory");
    __syncthreads();
  }
  #undef STAGE

  if (ACCUM || F32OUT){
    float* Cg = (float*)Cp + (long)g*cstride;
    #pragma unroll
    for (int ni=0;ni<4;ni++){
      int col = blockIdx.y*128 + wc*64 + ni*16 + lc;
      float bv = HASBIAS ? biasg[col] : 0.0f;
      #pragma unroll
      for (int mi=0;mi<4;mi++){
        int row = blockIdx.x*128 + wr*64 + mi*16 + lr*4;
        #pragma unroll
        for (int j=0;j<4;j++){
          float v = acc[mi][ni][j] + bv;
          if (GELU) v = gelu_f(v);
          if (ACCUM) Cg[(long)(row+j)*ldc + col] += v;
          else       Cg[(long)(row+j)*ldc + col] = v;
        }
      }
    }
  } else {
    __hip_bfloat16* Cg = (__hip_bfloat16*)Cp + (long)g*cstride;
    #pragma unroll
    for (int ni=0;ni<4;ni++){
      int col = blockIdx.y*128 + wc*64 + ni*16 + lc;
      float bv = HASBIAS ? biasg[col] : 0.0f;
      #pragma unroll
      for (int mi=0;mi<4;mi++){
        int row = blockIdx.x*128 + wr*64 + mi*16 + lr*4;
        #pragma unroll
        for (int j=0;j<4;j++){
          float v = acc[mi][ni][j] + bv;
          if (GELU) v = gelu_f(v);
          Cg[(long)(row+j)*ldc + col] = __float2bfloat16(v);
        }
      }
    }
  }
}

// K10: per-head softmax over 8 slots; logits fp32 (16384x128) -> P bf16 (16384x64)
__global__ __launch_bounds__(256) void softmax8_kernel(
    const float* __restrict__ logits, __hip_bfloat16* __restrict__ P)
{
  int t = blockIdx.x*32 + (threadIdx.x>>3);
  int h = threadIdx.x&7;
  const float* lr = logits + (long)t*128 + h*8;
  float4 a0 = *(const float4*)lr;
  float4 a1 = *(const float4*)(lr+4);
  float lgv[8] = {a0.x,a0.y,a0.z,a0.w,a1.x,a1.y,a1.z,a1.w};
  float mx = -1e30f;
  #pragma unroll
  for (int j=0;j<8;j++) mx = fmaxf(mx, lgv[j]);
  float e[8], s = 0.f;
  #pragma unroll
  for (int j=0;j<8;j++){ e[j] = __expf(lgv[j]-mx); s += e[j]; }
  float inv = 1.0f/s;
  short8 o;
  #pragma unroll
  for (int j=0;j<8;j++) o[j] = (short)bf16bits(e[j]*inv);
  *(short8*)(P + (long)t*64 + h*8) = o;
}

// K11: final scale+LN+scatter
__global__ __launch_bounds__(256) void final_kernel(
    const float* __restrict__ Xc, const int* __restrict__ cidx,
    const float* __restrict__ pw, const float* __restrict__ fln_g,
    const float* __restrict__ fln_b, float* __restrict__ out)
{
  long slot = (long)blockIdx.x*8 + (threadIdx.x>>5);
  int l32 = threadIdx.x & 31;
  int b = (int)(slot>>12);
  int p = (int)((slot>>10)&3);
  int i = cidx[slot];
  float pwv = pw[b*PP+p];
  const float* xr = Xc + slot*DD + l32*8;
  float4 v0 = *(const float4*)xr;
  float4 v1 = *(const float4*)(xr+4);
  float vv[8] = {v0.x,v0.y,v0.z,v0.w,v1.x,v1.y,v1.z,v1.w};
  #pragma unroll
  for (int k=0;k<8;k++) vv[k] *= pwv;
  float s = 0.f;
  #pragma unroll
  for (int k=0;k<8;k++) s += vv[k];
  #pragma unroll
  for (int mk=16; mk; mk>>=1) s += __shfl_xor(s, mk);
  float mu = s*(1.0f/256.0f);
  float q = 0.f;
  #pragma unroll
  for (int k=0;k<8;k++){ float d = vv[k]-mu; q += d*d; }
  #pragma unroll
  for (int mk=16; mk; mk>>=1) q += __shfl_xor(q, mk);
  float rs = rsqrtf(q*(1.0f/256.0f)+1e-5f);
  float* op = out + ((long)b*NN+i)*DD + l32*8;
  float4 o0, o1;
  o0.x = (vv[0]-mu)*rs*fln_g[l32*8+0]+fln_b[l32*8+0];
  o0.y = (vv[1]-mu)*rs*fln_g[l32*8+1]+fln_b[l32*8+1];
  o0.z = (vv[2]-mu)*rs*fln_g[l32*8+2]+fln_b[l32*8+2];
  o0.w = (vv[3]-mu)*rs*fln_g[l32*8+3]+fln_b[l32*8+3];
  o1.x = (vv[4]-mu)*rs*fln_g[l32*8+4]+fln_b[l32*8+4];
  o1.y = (vv[5]-mu)*rs*fln_g[l32*8+5]+fln_b[l32*8+5];
  o1.z = (vv[6]-mu)*rs*fln_g[l32*8+6]+fln_b[l32*8+6];
  o1.w = (vv[7]-mu)*rs*fln_g[l32*8+7]+fln_b[l32*8+7];
  *(float4*)op = o0;
  *(float4*)(op+4) = o1;
}

extern "C" void kernel_launch(void* const* d_in, const int* in_sizes, int n_in,
                              void* d_out, int out_size, void* d_ws, size_t ws_size,
                              hipStream_t stream)
{
  (void)in_sizes; (void)n_in; (void)out_size; (void)ws_size;
  const float* x     =(const float*)d_in[0];
  const float* m     =(const float*)d_in[1];
  const float* proj_w=(const float*)d_in[2];
  const float* proj_b=(const float*)d_in[3];
  const float* lnp_g =(const float*)d_in[4];
  const float* lnp_b =(const float*)d_in[5];
  const float* sq_w  =(const float*)d_in[6];
  const float* sq_b  =(const float*)d_in[7];
  const float* sk_w  =(const float*)d_in[8];
  const float* sk_b  =(const float*)d_in[9];
  const float* sv_w  =(const float*)d_in[10];
  const float* sv_b  =(const float*)d_in[11];
  const float* an_g  =(const float*)d_in[12];
  const float* an_b  =(const float*)d_in[13];
  const float* wq    =(const float*)d_in[14];
  const float* wk    =(const float*)d_in[15];
  const float* wv    =(const float*)d_in[16];
  const float* wo    =(const float*)d_in[17];
  const float* wo_b  =(const float*)d_in[18];
  const float* fn_g  =(const float*)d_in[19];
  const float* fn_b  =(const float*)d_in[20];
  const float* w1    =(const float*)d_in[21];
  const float* b1    =(const float*)d_in[22];
  const float* w2    =(const float*)d_in[23];
  const float* b2    =(const float*)d_in[24];
  const float* fln_g =(const float*)d_in[25];
  const float* fln_b =(const float*)d_in[26];
  float* out = (float*)d_out;

  float* ws = (float*)d_ws;
  float* tokens  = ws;  ws += 4194304;  // 16 MB (also start of actF 32MB span)
  float* logitsF = ws;  ws += 2097152;  // 8 MB fp32 16384x128
  float* Pbuff   = ws;  ws += 524288;   // 2 MB bf16 16384x64
  ws += 1572864;                        // 6 MB spill to complete actF 32MB span
  float* Xc      = ws;  ws += 4194304;  // fp32 residual
  float* actAf   = ws;  ws += 2097152;  // bf16 16384x256
  float* wqTf    = ws;  ws += 524288;
  float* w1Tf    = ws;  ws += 1048576;
  float* w2Tf    = ws;  ws += 1048576;
  float* qkPadf  = ws;  ws += 524288;   // bf16 [2][16][128][256]
  float* vwoTf   = ws;  ws += 262144;   // bf16 [2][16][256][64]
  float* kvk     = ws;  ws += 131072;
  float* kvv     = ws;  ws += 131072;
  float* kk2     = ws;  ws += 8192;
  float* kb      = ws;  ws += 32;
  float* vsc     = ws;  ws += 64;
  float* scores  = ws;  ws += 16384;
  float* pw      = ws;  ws += 16;
  int* rank      = (int*)ws;  ws += 16384;
  int* cidx      = (int*)ws;  ws += 16384;

  __hip_bfloat16* actA  = (__hip_bfloat16*)actAf;
  __hip_bfloat16* actF  = (__hip_bfloat16*)tokens;   // 16384x1024 bf16 span
  __hip_bfloat16* Pb    = (__hip_bfloat16*)Pbuff;
  __hip_bfloat16* wqT   = (__hip_bfloat16*)wqTf;
  __hip_bfloat16* w1T   = (__hip_bfloat16*)w1Tf;
  __hip_bfloat16* w2T   = (__hip_bfloat16*)w2Tf;
  __hip_bfloat16* qkPad = (__hip_bfloat16*)qkPadf;
  __hip_bfloat16* vwoT  = (__hip_bfloat16*)vwoTf;

  hipMemsetAsync(rank, 0, BB*NN*sizeof(int), stream);
  scorer_kk2_kernel<<<32,256,0,stream>>>(m, sk_w, sk_b, sv_w, sv_b, sq_w, sq_b,
                                         kk2, kb, vsc);
  proj_ln_score_kernel<<<1024,256,0,stream>>>(x, proj_w, proj_b, lnp_g, lnp_b,
                                              kk2, kb, vsc, tokens, scores);
  rank_partial_kernel<<<1024,256,0,stream>>>(scores, rank);
  rank_finalize_kernel<<<64,256,0,stream>>>(rank, cidx);
  pscore_pw_kernel<<<1,1024,0,stream>>>(scores, cidx, pw);
  kv_kernel<<<256,512,0,stream>>>(m, an_g, an_b, wk, wv, kvk, kvv);
  wconv_all_kernel<<<1280,256,0,stream>>>(wq, w1, w2, wqT, w1T, w2T);
  qkvwo_kernel<<<256,256,0,stream>>>(kvk, kvv, wqT, wo, qkPad, vwoT);
  gather_ln_kernel<<<2048,256,0,stream>>>(tokens, cidx, Xc, actA, an_g, an_b);

  for (int l=0;l<LL;l++){
    if (l > 0)
      ln_rows_kernel<<<2048,256,0,stream>>>(Xc, actA, an_g + l*DD, an_b + l*DD);
    // logits = xn @ qk^T  (1024x128(pad)x256 per group) -> fp32
    mfma_gemm<false,false,false,true,true><<<dim3(8,1,16),256,0,stream>>>(
        actA, (long)SS*DD, DD, qkPad + (long)l*16*128*256, (long)128*256,
        nullptr, 0, logitsF, 128, (long)SS*128);
    softmax8_kernel<<<512,256,0,stream>>>(logitsF, Pb);
    // Xc += P @ vwoT^T + wo_b  (1024x256x64 per group)
    mfma_gemm<true,false,true,true,false><<<dim3(8,2,16),256,0,stream>>>(
        Pb, (long)SS*64, 64, vwoT + (long)l*16*256*64, (long)256*64,
        wo_b + l*DD, LL*DD, Xc, DD, (long)SS*DD);
    ln_rows_kernel<<<2048,256,0,stream>>>(Xc, actA, fn_g + l*DD, fn_b + l*DD);
    // F = gelu(h @ w1 + b1)
    mfma_gemm<true,true,false,false,false><<<dim3(8,8,16),256,0,stream>>>(
        actA, (long)SS*DD, DD, w1T + (long)l*FFD*DD, (long)LL*FFD*DD,
        b1 + l*FFD, LL*FFD, actF, FFD, (long)SS*FFD);
    // Xc += F @ w2 + b2
    mfma_gemm<true,false,true,false,false><<<dim3(8,2,16),256,0,stream>>>(
        actF, (long)SS*FFD, FFD, w2T + (long)l*DD*FFD, (long)LL*DD*FFD,
        b2 + l*DD, LL*DD, Xc, DD, (long)SS*DD);
  }
  final_kernel<<<2048,256,0,stream>>>(Xc, cidx, pw, fln_g, fln_b, out);
}

// Round 11
// 299.353 us; speedup vs baseline: 1.3227x; 1.0860x over previous
//
#include <hip/hip_runtime.h>
#include <hip/hip_bf16.h>
#include <math.h>

// Problem constants
#define BB 4
#define CC 128
#define NN 4096      // H*W
#define DD 256
#define INNER 512
#define FFD 1024
#define PP 4
#define LL 2
#define NT 8
#define SS 1024      // NN/PP
#define SCALE 0.0625f // 1/sqrt(256)

typedef __attribute__((ext_vector_type(8))) short bf16x8;
typedef __attribute__((ext_vector_type(8))) short short8;
typedef __attribute__((ext_vector_type(4))) float f32x4;

#define GLD_LDS16(g, l) __builtin_amdgcn_global_load_lds( \
    (const __attribute__((address_space(1))) void*)(g), \
    (__attribute__((address_space(3))) void*)(l), 16, 0, 0)

template<int NW>
__device__ inline float block_sum(float v, float* sbuf){
  #pragma unroll
  for (int mk=32; mk; mk>>=1) v += __shfl_xor(v, mk);
  int w = threadIdx.x>>6;
  if ((threadIdx.x&63)==0) sbuf[w]=v;
  __syncthreads();
  float r = 0.f;
  #pragma unroll
  for (int k=0;k<NW;k++) r += sbuf[k];
  __syncthreads();
  return r;
}

__device__ inline unsigned short bf16bits(float v){
  __hip_bfloat16 t = __float2bfloat16(v);
  unsigned short u;
  __builtin_memcpy(&u, &t, 2);
  return u;
}
__device__ inline float bf2f(unsigned short u){
  unsigned int x = ((unsigned int)u)<<16;
  float f;
  __builtin_memcpy(&f, &x, 4);
  return f;
}

// fast GELU: erf via Abramowitz-Stegun 7.1.26 (|eps| <= 1.5e-7)
__device__ inline float gelu_f(float x){
  float z  = x * 0.70710678118654752440f;
  float az = fabsf(z);
  float t  = 1.0f / (1.0f + 0.3275911f*az);
  float y  = t*(0.254829592f + t*(-0.284496736f + t*(1.421413741f +
             t*(-1.453152027f + t*1.061405429f))));
  float erfv = 1.0f - y*__expf(-az*az);
  erfv = (z < 0.0f) ? -erfv : erfv;
  return 0.5f*x*(1.0f+erfv);
}

// K2: merged scorer: ksc (LDS only), then kk2/kb/vsc outputs
__global__ __launch_bounds__(256) void scorer_kk2_kernel(
    const float* __restrict__ m, const float* __restrict__ sk_w,
    const float* __restrict__ sk_b, const float* __restrict__ sv_w,
    const float* __restrict__ sv_b, const float* __restrict__ sq_w,
    const float* __restrict__ sq_b,
    float* __restrict__ kk2, float* __restrict__ kb, float* __restrict__ vsc)
{
  int bj = blockIdx.x;               // B*NT = 32
  int d = threadIdx.x;
  __shared__ float ms[256];
  __shared__ float ks[256];
  __shared__ float sbuf[4];
  ms[d] = m[bj*DD + d];
  __syncthreads();
  float acc=0.f;
  for(int c=0;c<DD;c++) acc = fmaf(ms[c], sk_w[c*DD + d], acc);
  ks[d] = acc + sk_b[d];
  float sv = block_sum<4>(ms[d]*sv_w[d], sbuf);
  if(d==0) vsc[bj] = sv + sv_b[0];
  __syncthreads();
  const float* wr = sq_w + (long)d*DD;
  float a2 = 0.f;
  for (int c=0; c<DD; c+=4){
    float4 wv = *(const float4*)(wr + c);
    a2 = fmaf(wv.x, ks[c+0], fmaf(wv.y, ks[c+1], fmaf(wv.z, ks[c+2], fmaf(wv.w, ks[c+3], a2))));
  }
  kk2[bj*DD + d] = a2;
  float kbv = block_sum<4>(sq_b[d]*ks[d], sbuf);
  if (d==0) kb[bj] = kbv;
}

// K1: tokens = LN(conv1x1(x)) AND scores via factored scorer. 16 tokens/block.
__global__ __launch_bounds__(256) void proj_ln_score_kernel(
    const float* __restrict__ x, const float* __restrict__ proj_w,
    const float* __restrict__ proj_b, const float* __restrict__ lnp_g,
    const float* __restrict__ lnp_b, const float* __restrict__ kk2,
    const float* __restrict__ kb, const float* __restrict__ vsc,
    float* __restrict__ tokens, float* __restrict__ scores)
{
  int b  = blockIdx.x >> 8;
  int n0 = (blockIdx.x & 255) * 16;
  int tid = threadIdx.x;
  __shared__ float xs[16][132];
  __shared__ float ys[16][260];
  __shared__ float kj[8][260];
  __shared__ float kbs[8], vs[8];
  __shared__ float mu_s[16], rs_s[16];
  __shared__ float lg[16][8];
  #pragma unroll
  for (int i=0;i<8;i++){
    int l = tid + i*256;
    int t = l & 15, c = l >> 4;
    xs[t][c] = x[(long)(b*CC + c)*NN + n0 + t];
  }
  #pragma unroll
  for (int i=0;i<8;i++){
    int idx = i*256 + tid;
    int r = idx >> 8, c = idx & 255;
    kj[r][c] = kk2[(b*NT + r)*DD + c];
  }
  if (tid < 8){ kbs[tid] = kb[b*NT+tid]; vs[tid] = vsc[b*NT+tid]; }
  __syncthreads();
  float acc[16];
  #pragma unroll
  for (int t=0;t<16;t++) acc[t]=0.f;
  for (int c0=0;c0<CC;c0+=4){
    float w0 = proj_w[(c0+0)*DD + tid];
    float w1_ = proj_w[(c0+1)*DD + tid];
    float w2_ = proj_w[(c0+2)*DD + tid];
    float w3_ = proj_w[(c0+3)*DD + tid];
    #pragma unroll
    for (int t=0;t<16;t++){
      float4 xv = *(const float4*)&xs[t][c0];
      acc[t] = fmaf(xv.x,w0,fmaf(xv.y,w1_,fmaf(xv.z,w2_,fmaf(xv.w,w3_,acc[t]))));
    }
  }
  float pb = proj_b[tid];
  #pragma unroll
  for (int t=0;t<16;t++) ys[t][tid] = acc[t] + pb;
  __syncthreads();
  int w = tid>>6, lane = tid&63;
  for (int k=0;k<4;k++){
    int t = w*4+k;
    float s = ys[t][lane] + ys[t][lane+64] + ys[t][lane+128] + ys[t][lane+192];
    #pragma unroll
    for (int mk=32; mk; mk>>=1) s += __shfl_xor(s, mk);
    float mu = s*(1.0f/256.0f);
    float d0=ys[t][lane]-mu, d1=ys[t][lane+64]-mu, d2=ys[t][lane+128]-mu, d3=ys[t][lane+192]-mu;
    float q = d0*d0+d1*d1+d2*d2+d3*d3;
    #pragma unroll
    for (int mk=32; mk; mk>>=1) q += __shfl_xor(q, mk);
    if (lane==0){ mu_s[t]=mu; rs_s[t]=rsqrtf(q*(1.0f/256.0f)+1e-5f); }
  }
  __syncthreads();
  float g = lnp_g[tid], be = lnp_b[tid];
  #pragma unroll
  for (int t=0;t<16;t++){
    float nv = (ys[t][tid]-mu_s[t])*rs_s[t]*g + be;
    tokens[((long)(b*NN + n0 + t))*DD + tid] = nv;
    ys[t][tid] = nv;
  }
  __syncthreads();
  if (tid < 128){
    int t = tid>>3, j = tid&7;
    float a2 = 0.f;
    for (int c0=0;c0<DD;c0+=4){
      float4 tv = *(const float4*)&ys[t][c0];
      float4 kv = *(const float4*)&kj[j][c0];
      a2 = fmaf(tv.x,kv.x,fmaf(tv.y,kv.y,fmaf(tv.z,kv.z,fmaf(tv.w,kv.w,a2))));
    }
    lg[t][j] = (a2 + kbs[j]) * SCALE;
  }
  __syncthreads();
  if (tid < 16){
    float mx=-1e30f;
    #pragma unroll
    for(int j=0;j<NT;j++) mx=fmaxf(mx,lg[tid][j]);
    float s=0.f, sc=0.f;
    #pragma unroll
    for(int j=0;j<NT;j++){ float e=__expf(lg[tid][j]-mx); s+=e; sc+=e*vs[j]; }
    scores[b*NN + n0 + tid] = sc/s;
  }
}

// K3a: partial ranks
__global__ __launch_bounds__(256) void rank_partial_kernel(
    const float* __restrict__ scores, int* __restrict__ rank)
{
  int b  = blockIdx.x >> 8;
  int it = (blockIdx.x >> 4) & 15;
  int jt = blockIdx.x & 15;
  int i = it*256 + threadIdx.x;
  float si = scores[b*NN + i];
  __shared__ float ss[256];
  ss[threadIdx.x] = scores[b*NN + jt*256 + threadIdx.x];
  __syncthreads();
  int jbase = jt*256;
  int cnt = 0;
  #pragma unroll 4
  for (int j=0;j<256;j++){
    float sj = ss[j];
    cnt += (sj > si) || (sj == si && (jbase+j) < i);
  }
  atomicAdd(&rank[b*NN+i], cnt);
}

// K3b
__global__ __launch_bounds__(256) void rank_finalize_kernel(
    const int* __restrict__ rank, int* __restrict__ cidx)
{
  int b = blockIdx.x >> 4;
  int i = (blockIdx.x & 15)*256 + threadIdx.x;
  int rk = rank[b*NN + i];
  int p = rk >> 10;
  cidx[(b*PP + p)*SS + (rk & (SS-1))] = i;
}

// K4
__global__ __launch_bounds__(1024) void pscore_pw_kernel(
    const float* __restrict__ scores, const int* __restrict__ cidx,
    float* __restrict__ pw)
{
  __shared__ float ps[16];
  int wv = threadIdx.x>>6;
  int lane = threadIdx.x&63;
  int b = wv>>2;
  float acc=0.f;
  for (int s=lane; s<SS; s+=64) acc += scores[b*NN + cidx[wv*SS + s]];
  #pragma unroll
  for (int mk=32; mk; mk>>=1) acc += __shfl_xor(acc, mk);
  if (lane==0) ps[wv] = acc*(1.0f/(float)SS);
  __syncthreads();
  if (threadIdx.x < BB){
    int bb = threadIdx.x;
    float mx=-1e30f;
    #pragma unroll
    for(int p=0;p<PP;p++) mx=fmaxf(mx,ps[bb*PP+p]);
    float s=0.f,e[PP];
    #pragma unroll
    for(int p=0;p<PP;p++){ e[p]=__expf(ps[bb*PP+p]-mx); s+=e[p]; }
    #pragma unroll
    for(int p=0;p<PP;p++) pw[bb*PP+p]=e[p]/s;
  }
}

// K6: gather + LN(an[p,0]) fused
__global__ __launch_bounds__(256) void gather_ln_kernel(
    const float* __restrict__ tokens, const int* __restrict__ cidx,
    float* __restrict__ Xc, __hip_bfloat16* __restrict__ Y,
    const float* __restrict__ gamma, const float* __restrict__ beta)
{
  long slot = (long)blockIdx.x*8 + (threadIdx.x>>5);
  int l32 = threadIdx.x & 31;
  int b = (int)(slot >> 12);
  int p = (int)((slot>>10)&3);
  int i = cidx[slot];
  const float* src = tokens + ((long)b*NN + i)*DD + l32*8;
  float4 v0 = *(const float4*)src;
  float4 v1 = *(const float4*)(src+4);
  *(float4*)(Xc + slot*DD + l32*8) = v0;
  *(float4*)(Xc + slot*DD + l32*8 + 4) = v1;
  float s = v0.x+v0.y+v0.z+v0.w+v1.x+v1.y+v1.z+v1.w;
  #pragma unroll
  for (int mk=16; mk; mk>>=1) s += __shfl_xor(s, mk);
  float mu = s*(1.0f/256.0f);
  float vv[8] = {v0.x,v0.y,v0.z,v0.w,v1.x,v1.y,v1.z,v1.w};
  float q = 0.f;
  #pragma unroll
  for (int k=0;k<8;k++){ float d = vv[k]-mu; q += d*d; }
  #pragma unroll
  for (int mk=16; mk; mk>>=1) q += __shfl_xor(q, mk);
  float rs = rsqrtf(q*(1.0f/256.0f)+1e-5f);
  short8 o;
  #pragma unroll
  for (int k=0;k<8;k++){
    int d = l32*8+k;
    o[k] = (short)bf16bits((vv[k]-mu)*rs*gamma[p*(LL*DD)+d]+beta[p*(LL*DD)+d]);
  }
  *(short8*)(Y + slot*DD + l32*8) = o;
}

// K7: decoder K/V precompute (plain layout)
__global__ __launch_bounds__(512) void kv_kernel(
    const float* __restrict__ m, const float* __restrict__ an_g,
    const float* __restrict__ an_b, const float* __restrict__ wk,
    const float* __restrict__ wv, float* __restrict__ kvk, float* __restrict__ kvv)
{
  int idx = blockIdx.x;              // (pl*B + b)*NT + j, grid 256
  int j = idx & 7, b = (idx>>3)&3, pl = idx>>5;
  int tid = threadIdx.x;
  __shared__ float mn[256];
  __shared__ float sbuf[8];
  float v = (tid<256) ? m[(b*NT+j)*DD + tid] : 0.0f;
  float s = block_sum<8>(v, sbuf);
  float mu = s*(1.0f/256.0f);
  float dv = (tid<256)? v-mu : 0.0f;
  float q = block_sum<8>(dv*dv, sbuf);
  float rs = rsqrtf(q*(1.0f/256.0f)+1e-5f);
  if (tid<256) mn[tid] = dv*rs*an_g[pl*DD+tid] + an_b[pl*DD+tid];
  __syncthreads();
  float ka=0.f, va=0.f;
  for (int c=0;c<DD;c++){
    float mc = mn[c];
    ka = fmaf(mc, wk[((long)pl*DD + c)*INNER + tid], ka);
    va = fmaf(mc, wv[((long)pl*DD + c)*INNER + tid], va);
  }
  long off = ((long)pl*BB + b)*(NT*INNER) + j*INNER + tid;
  kvk[off]=ka; kvv[off]=va;
}

// K8: rowwise LN -> bf16
__global__ __launch_bounds__(256) void ln_rows_kernel(
    const float* __restrict__ X, __hip_bfloat16* __restrict__ Y,
    const float* __restrict__ gamma, const float* __restrict__ beta)
{
  long row = (long)blockIdx.x*8 + (threadIdx.x>>5);
  int l32 = threadIdx.x & 31;
  int p = (int)((row>>10)&3);
  const float* xr = X + row*DD + l32*8;
  float4 v0 = *(const float4*)xr;
  float4 v1 = *(const float4*)(xr+4);
  float s = v0.x+v0.y+v0.z+v0.w+v1.x+v1.y+v1.z+v1.w;
  #pragma unroll
  for (int mk=16; mk; mk>>=1) s += __shfl_xor(s, mk);
  float mu = s*(1.0f/256.0f);
  float vv[8] = {v0.x,v0.y,v0.z,v0.w,v1.x,v1.y,v1.z,v1.w};
  float q = 0.f;
  #pragma unroll
  for (int k=0;k<8;k++){ float d = vv[k]-mu; q += d*d; }
  #pragma unroll
  for (int mk=16; mk; mk>>=1) q += __shfl_xor(q, mk);
  float rs = rsqrtf(q*(1.0f/256.0f)+1e-5f);
  short8 o;
  #pragma unroll
  for (int k=0;k<8;k++){
    int d = l32*8+k;
    o[k] = (short)bf16bits((vv[k]-mu)*rs*gamma[p*(LL*DD)+d]+beta[p*(LL*DD)+d]);
  }
  *(short8*)(Y + row*DD + l32*8) = o;
}

// Kw: wq/w1/w2 -> bf16 transposed [pl][N][K]
__global__ __launch_bounds__(256) void wconv_all_kernel(
    const float* __restrict__ wq, const float* __restrict__ w1,
    const float* __restrict__ w2,
    __hip_bfloat16* __restrict__ wqT, __hip_bfloat16* __restrict__ w1T,
    __hip_bfloat16* __restrict__ w2T)
{
  int z = blockIdx.x;
  const float* src; __hip_bfloat16* dst; int K, N, rel;
  if (z < 256)      { src=wq; dst=wqT; K=DD;   N=INNER; rel=z; }
  else if (z < 768) { src=w1; dst=w1T; K=DD;   N=FFD;   rel=z-256; }
  else              { src=w2; dst=w2T; K=FFD;  N=DD;    rel=z-768; }
  int tn = N>>6, tk = K>>6, per = tn*tk;
  int pl = rel/per, r2 = rel%per;
  int n0 = (r2%tn)*64, k0 = (r2/tn)*64;
  __shared__ float t[64][65];
  int tid = threadIdx.x;
  #pragma unroll
  for (int i=0;i<16;i++){
    int idx = i*256+tid;
    int kk = idx>>6, nn = idx&63;
    t[kk][nn] = src[((long)pl*K + k0+kk)*N + n0+nn];
  }
  __syncthreads();
  #pragma unroll
  for (int i=0;i<16;i++){
    int idx = i*256+tid;
    int nn = idx>>6, kk = idx&63;
    dst[((long)pl*N + n0+nn)*K + k0+kk] = __float2bfloat16(t[kk][nn]);
  }
}

// Kqv: per-(z,head) block: qk rows h*8..h*8+7 (SCALE folded) + vwoT cols h*8..+7
__global__ __launch_bounds__(256) void qkvwo_kernel(
    const float* __restrict__ kvk, const float* __restrict__ kvv,
    const __hip_bfloat16* __restrict__ wqT, const float* __restrict__ wo,
    __hip_bfloat16* __restrict__ qkBuf, __hip_bfloat16* __restrict__ vwoT)
{
  int zz = blockIdx.x;               // z*8 + h
  int z = zz>>3, h = zz&7;
  int l = z>>4, g = z&15;
  int b = g>>2, p = g&3;
  int pl = p*LL + l;
  int c = threadIdx.x;
  __shared__ float kL[8][64];
  __shared__ float vL[8][64];
  {
    int j0 = c>>6, d0 = c&63;
    long off = ((long)pl*BB + b)*(NT*INNER) + h*64 + d0;
    kL[j0][d0]   = kvk[off + j0*INNER];
    vL[j0][d0]   = kvv[off + j0*INNER];
    kL[j0+4][d0] = kvk[off + (j0+4)*INNER];
    vL[j0+4][d0] = kvv[off + (j0+4)*INNER];
  }
  __syncthreads();
  float qa[8] = {0,0,0,0,0,0,0,0};
  float va[8] = {0,0,0,0,0,0,0,0};
  const __hip_bfloat16* wqp = wqT + ((long)pl*INNER + h*64)*DD + c;
  const float* wop = wo + ((long)pl*INNER + h*64)*DD + c;
  for (int d=0; d<64; d++){
    float wqv = bf2f(*(const unsigned short*)(wqp + (long)d*DD));
    float wov = wop[(long)d*DD];
    #pragma unroll
    for (int j=0;j<8;j++){
      qa[j] = fmaf(kL[j][d], wqv, qa[j]);
      va[j] = fmaf(vL[j][d], wov, va[j]);
    }
  }
  __hip_bfloat16* qkg = qkBuf + (long)z*64*256;
  __hip_bfloat16* vwg = vwoT + (long)z*256*64;
  #pragma unroll
  for (int j=0;j<8;j++)
    qkg[(h*8+j)*256 + c] = __float2bfloat16(qa[j]*SCALE);
  short8 o;
  #pragma unroll
  for (int j=0;j<8;j++) o[j] = (short)bf16bits(va[j]);
  *(short8*)(vwg + c*64 + h*8) = o;
}

// K9: MFMA bf16 GEMM, 2-phase double-buffered. Grid (rowTiles, colTiles, g)
template<bool HASBIAS, bool GELU, bool ACCUM>
__global__ __launch_bounds__(256) void mfma_gemm(
    const __hip_bfloat16* __restrict__ A, long astride, int K,
    const __hip_bfloat16* __restrict__ BT, long bpstride,
    const float* __restrict__ bias, int bias_pstride,
    void* __restrict__ Cp, int ldc, long cstride)
{
  int g = blockIdx.z;
  int p = g & 3;
  const __hip_bfloat16* Ag = A  + (long)g*astride + (long)blockIdx.x*128*K;
  const __hip_bfloat16* Bg = BT + (long)p*bpstride + (long)blockIdx.y*128*K;
  const float* biasg = HASBIAS ? (bias + (long)p*bias_pstride) : nullptr;

  __shared__ __align__(16) __hip_bfloat16 Asm[2][128*64];
  __shared__ __align__(16) __hip_bfloat16 Bsm[2][128*64];

  int tid = threadIdx.x;
  int w = tid>>6, lane = tid&63;
  int wr = w>>1, wc = w&1;
  int lr = lane>>4, lc = lane&15;
  int ldsbase = tid & ~63;

  const __hip_bfloat16* aseg[4];
  const __hip_bfloat16* bseg[4];
  #pragma unroll
  for (int i=0;i<4;i++){
    int seg = i*256 + tid;
    int r = seg>>3, sl = seg&7;
    int sg = sl ^ (r&7);
    aseg[i] = Ag + (long)r*K + sg*8;
    bseg[i] = Bg + (long)r*K + sg*8;
  }

  f32x4 acc[4][4] = {};
  int nt = K >> 6;

  #define STAGE(buf) do { \
    _Pragma("unroll") \
    for (int i_=0;i_<4;i_++) \
      GLD_LDS16(aseg[i_], &Asm[buf][(i_*256 + ldsbase)*8]); \
    _Pragma("unroll") \
    for (int i_=0;i_<4;i_++) \
      GLD_LDS16(bseg[i_], &Bsm[buf][(i_*256 + ldsbase)*8]); \
    _Pragma("unroll") \
    for (int i_=0;i_<4;i_++){ aseg[i_] += 64; bseg[i_] += 64; } \
  } while(0)

  STAGE(0);
  asm volatile("s_waitcnt vmcnt(0)" ::: "memory");
  __syncthreads();

  for (int t=0; t<nt; t++){
    int cur = t & 1;
    if (t+1 < nt) STAGE(cur^1);
    #pragma unroll
    for (int kc=0;kc<2;kc++){
      bf16x8 af[4], bfr[4];
      #pragma unroll
      for (int mi=0;mi<4;mi++){
        int r = wr*64 + mi*16 + lc;
        int s = kc*4 + lr;
        af[mi] = *(const bf16x8*)(&Asm[cur][r*64 + (s ^ (r&7))*8]);
      }
      #pragma unroll
      for (int ni=0;ni<4;ni++){
        int r = wc*64 + ni*16 + lc;
        int s = kc*4 + lr;
        bfr[ni] = *(const bf16x8*)(&Bsm[cur][r*64 + (s ^ (r&7))*8]);
      }
      #pragma unroll
      for (int mi=0;mi<4;mi++)
        #pragma unroll
        for (int ni=0;ni<4;ni++)
          acc[mi][ni] = __builtin_amdgcn_mfma_f32_16x16x32_bf16(af[mi], bfr[ni], acc[mi][ni], 0, 0, 0);
    }
    if (t+1 < nt) asm volatile("s_waitcnt vmcnt(0)" ::: "memory");
    __syncthreads();
  }
  #undef STAGE

  if (ACCUM){
    float* Cg = (float*)Cp + (long)g*cstride;
    #pragma unroll
    for (int ni=0;ni<4;ni++){
      int col = blockIdx.y*128 + wc*64 + ni*16 + lc;
      float bv = HASBIAS ? biasg[col] : 0.0f;
      #pragma unroll
      for (int mi=0;mi<4;mi++){
        int row = blockIdx.x*128 + wr*64 + mi*16 + lr*4;
        #pragma unroll
        for (int j=0;j<4;j++){
          float v = acc[mi][ni][j] + bv;
          if (GELU) v = gelu_f(v);
          Cg[(long)(row+j)*ldc + col] += v;
        }
      }
    }
  } else {
    __hip_bfloat16* Cg = (__hip_bfloat16*)Cp + (long)g*cstride;
    #pragma unroll
    for (int ni=0;ni<4;ni++){
      int col = blockIdx.y*128 + wc*64 + ni*16 + lc;
      float bv = HASBIAS ? biasg[col] : 0.0f;
      #pragma unroll
      for (int mi=0;mi<4;mi++){
        int row = blockIdx.x*128 + wr*64 + mi*16 + lr*4;
        #pragma unroll
        for (int j=0;j<4;j++){
          float v = acc[mi][ni][j] + bv;
          if (GELU) v = gelu_f(v);
          Cg[(long)(row+j)*ldc + col] = __float2bfloat16(v);
        }
      }
    }
  }
}

// K10: FUSED attention: logits(64x64) -> softmax -> Xc += P @ vwoT^T + wo_b
// grid (16 rowblocks, 16 groups), 256 threads, 48 KB LDS
__global__ __launch_bounds__(256) void fused_attn_kernel(
    const __hip_bfloat16* __restrict__ actA,   // [16][1024][256]
    const __hip_bfloat16* __restrict__ qk,     // [16][64][256]  (this layer)
    const __hip_bfloat16* __restrict__ vwo,    // [16][256][64]  (this layer)
    const float* __restrict__ wo_bl,           // wo_b + l*DD (per-p stride LL*DD)
    float* __restrict__ Xc)
{
  int rb = blockIdx.x;               // row block (64 rows)
  int g  = blockIdx.y;
  int p  = g & 3;
  const __hip_bfloat16* Ag = actA + ((long)g*SS + rb*64)*DD;
  const __hip_bfloat16* Qg = qk  + (long)g*64*256;
  const __hip_bfloat16* Vg = vwo + (long)g*256*64;

  // LDS: [0,4096) A0 / P ; [4096,8192) A1 ; [8192,24576) qk / vwoT
  __shared__ __align__(16) __hip_bfloat16 sm[24576];
  int tid = threadIdx.x;
  int w = tid>>6, lane = tid&63;
  int lr = lane>>4, lc = lane&15;
  int ldsbase = tid & ~63;

  // ---- stage qk (fully) + A step 0 ----
  #pragma unroll
  for (int i=0;i<8;i++){
    int seg = i*256 + tid;          // 2048 segs: row=seg>>5, sl=seg&31
    int r = seg>>5, sl = seg&31;
    int sg = sl ^ (r&7);
    GLD_LDS16(Qg + (long)r*256 + sg*8, &sm[8192 + (i*256 + ldsbase)*8]);
  }
  #pragma unroll
  for (int i=0;i<2;i++){
    int seg = i*256 + tid;          // 512 segs: row=seg>>3, sl=seg&7
    int r = seg>>3, sl = seg&7;
    int sg = sl ^ (r&7);
    GLD_LDS16(Ag + (long)r*DD + sg*8, &sm[0 + (i*256 + ldsbase)*8]);
  }
  asm volatile("s_waitcnt vmcnt(0)" ::: "memory");
  __syncthreads();

  // ---- logits: wave w -> rows w*16..+15, cols 0..63; K=256 in 4 steps ----
  f32x4 acc1[4] = {};
  for (int t=0; t<4; t++){
    int cur = t&1;
    if (t+1 < 4){
      #pragma unroll
      for (int i=0;i<2;i++){
        int seg = i*256 + tid;
        int r = seg>>3, sl = seg&7;
        int sg = sl ^ (r&7);
        GLD_LDS16(Ag + (long)r*DD + (t+1)*64 + sg*8,
                  &sm[(cur^1)*4096 + (i*256 + ldsbase)*8]);
      }
    }
    #pragma unroll
    for (int kc=0;kc<2;kc++){
      int r = w*16 + lc;
      int s = kc*4 + lr;
      bf16x8 af = *(const bf16x8*)(&sm[cur*4096 + r*64 + (s ^ (r&7))*8]);
      #pragma unroll
      for (int ni=0;ni<4;ni++){
        int rb_ = ni*16 + lc;
        int sb = t*8 + kc*4 + lr;
        bf16x8 bfr = *(const bf16x8*)(&sm[8192 + rb_*256 + (sb ^ (rb_&7))*8]);
        acc1[ni] = __builtin_amdgcn_mfma_f32_16x16x32_bf16(af, bfr, acc1[ni], 0, 0, 0);
      }
    }
    if (t+1 < 4) asm volatile("s_waitcnt vmcnt(0)" ::: "memory");
    __syncthreads();
  }

  // ---- issue vwoT stage (into qk region, now dead) ----
  #pragma unroll
  for (int i=0;i<8;i++){
    int seg = i*256 + tid;          // 2048 segs: row=seg>>3, sl=seg&7
    int r = seg>>3, sl = seg&7;
    int sg = sl ^ (r&7);
    GLD_LDS16(Vg + (long)r*64 + sg*8, &sm[8192 + (i*256 + ldsbase)*8]);
  }

  // ---- softmax in-register: head h = cols h*8..h*8+7 -> lanes differing in bits 0-2 ----
  float pv[4][4];
  #pragma unroll
  for (int ni=0;ni<4;ni++){
    #pragma unroll
    for (int j=0;j<4;j++){
      float v = acc1[ni][j];
      float mx = v;
      mx = fmaxf(mx, __shfl_xor(mx,1));
      mx = fmaxf(mx, __shfl_xor(mx,2));
      mx = fmaxf(mx, __shfl_xor(mx,4));
      float e = __expf(v - mx);
      float ssum = e;
      ssum += __shfl_xor(ssum,1);
      ssum += __shfl_xor(ssum,2);
      ssum += __shfl_xor(ssum,4);
      pv[ni][j] = e / ssum;
    }
  }
  // write P (64x64 bf16, swizzled) into [0,4096)
  #pragma unroll
  for (int ni=0;ni<4;ni++){
    #pragma unroll
    for (int j=0;j<4;j++){
      int row = w*16 + lr*4 + j;
      int col = ni*16 + lc;
      int s = col>>3, e = col&7;
      sm[row*64 + ((s ^ (row&7))<<3) + e] = __float2bfloat16(pv[ni][j]);
    }
  }
  asm volatile("s_waitcnt vmcnt(0)" ::: "memory");
  __syncthreads();

  // ---- PV: wave w -> cols w*64..+63, rows 0..63; K=64 ----
  f32x4 acc2[4][4] = {};
  #pragma unroll
  for (int kc=0;kc<2;kc++){
    bf16x8 af[4], bfr[4];
    #pragma unroll
    for (int mi=0;mi<4;mi++){
      int r = mi*16 + lc;
      int s = kc*4 + lr;
      af[mi] = *(const bf16x8*)(&sm[r*64 + (s ^ (r&7))*8]);
    }
    #pragma unroll
    for (int ni=0;ni<4;ni++){
      int rb_ = w*64 + ni*16 + lc;
      int s = kc*4 + lr;
      bfr[ni] = *(const bf16x8*)(&sm[8192 + rb_*64 + (s ^ (rb_&7))*8]);
    }
    #pragma unroll
    for (int mi=0;mi<4;mi++)
      #pragma unroll
      for (int ni=0;ni<4;ni++)
        acc2[mi][ni] = __builtin_amdgcn_mfma_f32_16x16x32_bf16(af[mi], bfr[ni], acc2[mi][ni], 0, 0, 0);
  }

  float* Xg = Xc + (long)g*SS*DD + (long)rb*64*DD;
  #pragma unroll
  for (int ni=0;ni<4;ni++){
    int col = w*64 + ni*16 + lc;
    float bv = wo_bl[p*(LL*DD) + col];
    #pragma unroll
    for (int mi=0;mi<4;mi++){
      int row = mi*16 + lr*4;
      #pragma unroll
      for (int j=0;j<4;j++)
        Xg[(long)(row+j)*DD + col] += acc2[mi][ni][j] + bv;
    }
  }
}

// K11: final scale+LN+scatter
__global__ __launch_bounds__(256) void final_kernel(
    const float* __restrict__ Xc, const int* __restrict__ cidx,
    const float* __restrict__ pw, const float* __restrict__ fln_g,
    const float* __restrict__ fln_b, float* __restrict__ out)
{
  long slot = (long)blockIdx.x*8 + (threadIdx.x>>5);
  int l32 = threadIdx.x & 31;
  int b = (int)(slot>>12);
  int p = (int)((slot>>10)&3);
  int i = cidx[slot];
  float pwv = pw[b*PP+p];
  const float* xr = Xc + slot*DD + l32*8;
  float4 v0 = *(const float4*)xr;
  float4 v1 = *(const float4*)(xr+4);
  float vv[8] = {v0.x,v0.y,v0.z,v0.w,v1.x,v1.y,v1.z,v1.w};
  #pragma unroll
  for (int k=0;k<8;k++) vv[k] *= pwv;
  float s = 0.f;
  #pragma unroll
  for (int k=0;k<8;k++) s += vv[k];
  #pragma unroll
  for (int mk=16; mk; mk>>=1) s += __shfl_xor(s, mk);
  float mu = s*(1.0f/256.0f);
  float q = 0.f;
  #pragma unroll
  for (int k=0;k<8;k++){ float d = vv[k]-mu; q += d*d; }
  #pragma unroll
  for (int mk=16; mk; mk>>=1) q += __shfl_xor(q, mk);
  float rs = rsqrtf(q*(1.0f/256.0f)+1e-5f);
  float* op = out + ((long)b*NN+i)*DD + l32*8;
  float4 o0, o1;
  o0.x = (vv[0]-mu)*rs*fln_g[l32*8+0]+fln_b[l32*8+0];
  o0.y = (vv[1]-mu)*rs*fln_g[l32*8+1]+fln_b[l32*8+1];
  o0.z = (vv[2]-mu)*rs*fln_g[l32*8+2]+fln_b[l32*8+2];
  o0.w = (vv[3]-mu)*rs*fln_g[l32*8+3]+fln_b[l32*8+3];
  o1.x = (vv[4]-mu)*rs*fln_g[l32*8+4]+fln_b[l32*8+4];
  o1.y = (vv[5]-mu)*rs*fln_g[l32*8+5]+fln_b[l32*8+5];
  o1.z = (vv[6]-mu)*rs*fln_g[l32*8+6]+fln_b[l32*8+6];
  o1.w = (vv[7]-mu)*rs*fln_g[l32*8+7]+fln_b[l32*8+7];
  *(float4*)op = o0;
  *(float4*)(op+4) = o1;
}

extern "C" void kernel_launch(void* const* d_in, const int* in_sizes, int n_in,
                              void* d_out, int out_size, void* d_ws, size_t ws_size,
                              hipStream_t stream)
{
  (void)in_sizes; (void)n_in; (void)out_size; (void)ws_size;
  const float* x     =(const float*)d_in[0];
  const float* m     =(const float*)d_in[1];
  const float* proj_w=(const float*)d_in[2];
  const float* proj_b=(const float*)d_in[3];
  const float* lnp_g =(const float*)d_in[4];
  const float* lnp_b =(const float*)d_in[5];
  const float* sq_w  =(const float*)d_in[6];
  const float* sq_b  =(const float*)d_in[7];
  const float* sk_w  =(const float*)d_in[8];
  const float* sk_b  =(const float*)d_in[9];
  const float* sv_w  =(const float*)d_in[10];
  const float* sv_b  =(const float*)d_in[11];
  const float* an_g  =(const float*)d_in[12];
  const float* an_b  =(const float*)d_in[13];
  const float* wq    =(const float*)d_in[14];
  const float* wk    =(const float*)d_in[15];
  const float* wv    =(const float*)d_in[16];
  const float* wo    =(const float*)d_in[17];
  const float* wo_b  =(const float*)d_in[18];
  const float* fn_g  =(const float*)d_in[19];
  const float* fn_b  =(const float*)d_in[20];
  const float* w1    =(const float*)d_in[21];
  const float* b1    =(const float*)d_in[22];
  const float* w2    =(const float*)d_in[23];
  const float* b2    =(const float*)d_in[24];
  const float* fln_g =(const float*)d_in[25];
  const float* fln_b =(const float*)d_in[26];
  float* out = (float*)d_out;

  float* ws = (float*)d_ws;
  float* tokens  = ws;  ws += 4194304;  // 16 MB (start of actF 32MB span)
  ws += 4194304;                        // 16 MB actF second half
  float* Xc      = ws;  ws += 4194304;  // fp32 residual
  float* actAf   = ws;  ws += 2097152;  // bf16 16384x256
  float* wqTf    = ws;  ws += 524288;
  float* w1Tf    = ws;  ws += 1048576;
  float* w2Tf    = ws;  ws += 1048576;
  float* qkBf    = ws;  ws += 262144;   // bf16 [2][16][64][256]
  float* vwoTf   = ws;  ws += 262144;   // bf16 [2][16][256][64]
  float* kvk     = ws;  ws += 131072;
  float* kvv     = ws;  ws += 131072;
  float* kk2     = ws;  ws += 8192;
  float* kb      = ws;  ws += 32;
  float* vsc     = ws;  ws += 64;
  float* scores  = ws;  ws += 16384;
  float* pw      = ws;  ws += 16;
  int* rank      = (int*)ws;  ws += 16384;
  int* cidx      = (int*)ws;  ws += 16384;

  __hip_bfloat16* actA  = (__hip_bfloat16*)actAf;
  __hip_bfloat16* actF  = (__hip_bfloat16*)tokens;   // 16384x1024 bf16 span
  __hip_bfloat16* wqT   = (__hip_bfloat16*)wqTf;
  __hip_bfloat16* w1T   = (__hip_bfloat16*)w1Tf;
  __hip_bfloat16* w2T   = (__hip_bfloat16*)w2Tf;
  __hip_bfloat16* qkBuf = (__hip_bfloat16*)qkBf;
  __hip_bfloat16* vwoT  = (__hip_bfloat16*)vwoTf;

  hipMemsetAsync(rank, 0, BB*NN*sizeof(int), stream);
  scorer_kk2_kernel<<<32,256,0,stream>>>(m, sk_w, sk_b, sv_w, sv_b, sq_w, sq_b,
                                         kk2, kb, vsc);
  proj_ln_score_kernel<<<1024,256,0,stream>>>(x, proj_w, proj_b, lnp_g, lnp_b,
                                              kk2, kb, vsc, tokens, scores);
  rank_partial_kernel<<<1024,256,0,stream>>>(scores, rank);
  rank_finalize_kernel<<<64,256,0,stream>>>(rank, cidx);
  pscore_pw_kernel<<<1,1024,0,stream>>>(scores, cidx, pw);
  kv_kernel<<<256,512,0,stream>>>(m, an_g, an_b, wk, wv, kvk, kvv);
  wconv_all_kernel<<<1280,256,0,stream>>>(wq, w1, w2, wqT, w1T, w2T);
  qkvwo_kernel<<<256,256,0,stream>>>(kvk, kvv, wqT, wo, qkBuf, vwoT);
  gather_ln_kernel<<<2048,256,0,stream>>>(tokens, cidx, Xc, actA, an_g, an_b);

  for (int l=0;l<LL;l++){
    if (l > 0)
      ln_rows_kernel<<<2048,256,0,stream>>>(Xc, actA, an_g + l*DD, an_b + l*DD);
    // fused: logits -> softmax -> Xc += P@vwoT^T + wo_b
    fused_attn_kernel<<<dim3(16,16),256,0,stream>>>(
        actA, qkBuf + (long)l*16*64*256, vwoT + (long)l*16*256*64,
        wo_b + l*DD, Xc);
    ln_rows_kernel<<<2048,256,0,stream>>>(Xc, actA, fn_g + l*DD, fn_b + l*DD);
    // F = gelu(h @ w1 + b1)
    mfma_gemm<true,true,false><<<dim3(8,8,16),256,0,stream>>>(
        actA, (long)SS*DD, DD, w1T + (long)l*FFD*DD, (long)LL*FFD*DD,
        b1 + l*FFD, LL*FFD, actF, FFD, (long)SS*FFD);
    // Xc += F @ w2 + b2
    mfma_gemm<true,false,true><<<dim3(8,2,16),256,0,stream>>>(
        actF, (long)SS*FFD, FFD, w2T + (long)l*DD*FFD, (long)LL*DD*FFD,
        b2 + l*DD, LL*DD, Xc, DD, (long)SS*DD);
  }
  final_kernel<<<2048,256,0,stream>>>(Xc, cidx, pw, fln_g, fln_b, out);
}